// Round 1
// baseline (523.608 us; speedup 1.0000x reference)
//
#include <hip/hip_runtime.h>
#include <hip/hip_bf16.h>
#include <math.h>

#define DIV_UP(a,b) (((a)+(b)-1)/(b))

// ---------------- CSR build ----------------
__global__ void k_count_deg(const int* __restrict__ dst, int* __restrict__ deg, int E){
  int i = blockIdx.x*blockDim.x + threadIdx.x;
  if (i < E) atomicAdd(&deg[dst[i]], 1);
}

__global__ void k_scan(const int* __restrict__ deg, int* __restrict__ row_start,
                       int* __restrict__ cursor, int N){
  __shared__ int sums[1024];
  int tid = threadIdx.x;
  int chunk = (N + 1023) / 1024;
  int base = tid * chunk;
  int s = 0;
  for (int i = 0; i < chunk; i++){ int idx = base + i; if (idx < N) s += deg[idx]; }
  sums[tid] = s; __syncthreads();
  for (int off = 1; off < 1024; off <<= 1){
    int v = (tid >= off) ? sums[tid - off] : 0;
    __syncthreads();
    sums[tid] += v;
    __syncthreads();
  }
  int run = (tid == 0) ? 0 : sums[tid - 1];
  for (int i = 0; i < chunk; i++){
    int idx = base + i;
    if (idx < N){ row_start[idx] = run; cursor[idx] = run; run += deg[idx]; }
  }
  if (tid == 0) row_start[N] = sums[1023];
}

__global__ void k_fill(const int* __restrict__ dst, int* __restrict__ cursor,
                       int* __restrict__ edge_list, int E){
  int i = blockIdx.x*blockDim.x + threadIdx.x;
  if (i < E){ int p = atomicAdd(&cursor[dst[i]], 1); edge_list[p] = i; }
}

// ---------------- fp32 tiled GEMM: C[M,N] = A[M,K] @ B[K,N] ----------------
// BM=64, BN=64, BK=32, 256 threads, 4x4 micro-tile.
__global__ __launch_bounds__(256) void k_gemm(const float* __restrict__ A,
                                              const float* __restrict__ B,
                                              float* __restrict__ C,
                                              int M, int N, int K){
  __shared__ float As[32][68];  // [k][m], padded, rows 16B-aligned (68*4=272)
  __shared__ float Bs[32][68];  // [k][n]
  int tid = threadIdx.x;
  int tx = tid & 15, ty = tid >> 4;
  int m0 = blockIdx.x * 64, n0 = blockIdx.y * 64;
  float acc[4][4] = {};
  for (int k0 = 0; k0 < K; k0 += 32){
    #pragma unroll
    for (int i = 0; i < 2; i++){               // A tile 64x32, transposed store
      int q = tid + i*256;
      int row = q >> 3, c4 = q & 7;
      float4 a = make_float4(0.f,0.f,0.f,0.f);
      if (m0 + row < M) a = *(const float4*)&A[(size_t)(m0+row)*K + k0 + c4*4];
      As[c4*4+0][row] = a.x; As[c4*4+1][row] = a.y;
      As[c4*4+2][row] = a.z; As[c4*4+3][row] = a.w;
    }
    #pragma unroll
    for (int i = 0; i < 2; i++){               // B tile 32x64
      int q = tid + i*256;
      int row = q >> 4, c4 = q & 15;
      float4 b = *(const float4*)&B[(size_t)(k0+row)*N + n0 + c4*4];
      *(float4*)&Bs[row][c4*4] = b;
    }
    __syncthreads();
    #pragma unroll
    for (int kk = 0; kk < 32; kk++){
      float4 av = *(const float4*)&As[kk][ty*4];
      float4 bv = *(const float4*)&Bs[kk][tx*4];
      float a_[4] = {av.x, av.y, av.z, av.w};
      float b_[4] = {bv.x, bv.y, bv.z, bv.w};
      #pragma unroll
      for (int i = 0; i < 4; i++)
        #pragma unroll
        for (int j = 0; j < 4; j++)
          acc[i][j] += a_[i] * b_[j];
    }
    __syncthreads();
  }
  #pragma unroll
  for (int i = 0; i < 4; i++){
    int r = m0 + ty*4 + i;
    if (r < M)
      *(float4*)&C[(size_t)r*N + n0 + tx*4] =
          make_float4(acc[i][0], acc[i][1], acc[i][2], acc[i][3]);
  }
}

// ---------------- el/er dot products: one wave per (n,h), D=64 ----------------
template<int H>
__global__ __launch_bounds__(256) void k_attn(const float* __restrict__ feat,
      const float* __restrict__ al, const float* __restrict__ ar,
      float* __restrict__ el, float* __restrict__ er, int N){
  int w = (blockIdx.x*256 + threadIdx.x) >> 6;
  int lane = threadIdx.x & 63;
  if (w >= N*H) return;
  int n = w / H, h = w - n*H;
  float v = feat[(size_t)n*(H*64) + h*64 + lane];
  float pl = v * al[h*64 + lane];
  float pr = v * ar[h*64 + lane];
  #pragma unroll
  for (int o = 32; o; o >>= 1){ pl += __shfl_down(pl, o); pr += __shfl_down(pr, o); }
  if (lane == 0){ el[(size_t)n*H + h] = pl; er[(size_t)n*H + h] = pr; }
}

// ---------------- fused edge-softmax + aggregation: one wave per node ----------------
// out[n,h,d] = (sum_e feat[src_e,h,d]*exp(x_e,h - m_h)) / (sum_e exp(x_e,h - m_h)) + bias
// x = leaky_relu(el[src]+er[n], 0.2). D=64 fixed. H=4 -> lane owns 4 dims of head lane/16.
template<int H, bool RELU>
__global__ __launch_bounds__(256) void k_agg(const float* __restrict__ feat,
      const float* __restrict__ el, const float* __restrict__ er,
      const int* __restrict__ row_start, const int* __restrict__ edge_list,
      const int* __restrict__ src, const float* __restrict__ bias,
      float* __restrict__ out, int N){
  constexpr int LPH = 64 / H;
  int wid  = (blockIdx.x*256 + threadIdx.x) >> 6;
  int lane = threadIdx.x & 63;
  if (wid >= N) return;
  int n = wid;
  int h = lane / LPH;
  int rs = row_start[n], re = row_start[n+1];
  int deg = re - rs;

  float ern[H];
  #pragma unroll
  for (int t = 0; t < H; t++) ern[t] = er[(size_t)n*H + t];

  float acc[H];
  #pragma unroll
  for (int t = 0; t < H; t++) acc[t] = 0.f;
  float inv = 0.f;

  if (deg > 0){
    if (deg <= 64){
      int s = -1;
      float x[H];
      #pragma unroll
      for (int t = 0; t < H; t++) x[t] = -INFINITY;
      if (lane < deg){
        int e = edge_list[rs + lane];
        s = src[e];
        #pragma unroll
        for (int t = 0; t < H; t++){
          float xv = el[(size_t)s*H + t] + ern[t];
          x[t] = xv > 0.f ? xv : 0.2f*xv;
        }
      }
      float mm[H];
      #pragma unroll
      for (int t = 0; t < H; t++) mm[t] = x[t];
      #pragma unroll
      for (int o = 1; o < 64; o <<= 1){
        #pragma unroll
        for (int t = 0; t < H; t++) mm[t] = fmaxf(mm[t], __shfl_xor(mm[t], o));
      }
      float wgt[H];
      #pragma unroll
      for (int t = 0; t < H; t++) wgt[t] = (lane < deg) ? __expf(x[t]-mm[t]) : 0.f;
      float sw[H];
      #pragma unroll
      for (int t = 0; t < H; t++) sw[t] = wgt[t];
      #pragma unroll
      for (int o = 1; o < 64; o <<= 1){
        #pragma unroll
        for (int t = 0; t < H; t++) sw[t] += __shfl_xor(sw[t], o);
      }
      for (int i = 0; i < deg; i++){
        int sb = __shfl(s, i);
        if constexpr (H == 4){
          float w0=__shfl(wgt[0],i), w1=__shfl(wgt[1],i), w2=__shfl(wgt[2],i), w3=__shfl(wgt[3],i);
          float wb = (h==0)?w0:(h==1)?w1:(h==2)?w2:w3;
          float4 f = *(const float4*)&feat[(size_t)sb*256 + lane*4];
          acc[0] += f.x*wb; acc[1] += f.y*wb; acc[2] += f.z*wb; acc[3] += f.w*wb;
        } else {
          float wb = __shfl(wgt[0], i);
          acc[0] += feat[(size_t)sb*64 + lane] * wb;
        }
      }
      float ss = (H==4) ? ((h==0)?sw[0]:(h==1)?sw[1]:(h==2)?sw[2]:sw[3]) : sw[0];
      inv = 1.f / ss;
    } else {
      // chunked slow path (deg > 64)
      float mm[H];
      #pragma unroll
      for (int t = 0; t < H; t++) mm[t] = -INFINITY;
      for (int base = rs; base < re; base += 64){
        int cnt = min(64, re - base);
        if (lane < cnt){
          int e = edge_list[base + lane];
          int s = src[e];
          #pragma unroll
          for (int t = 0; t < H; t++){
            float xv = el[(size_t)s*H + t] + ern[t];
            xv = xv > 0.f ? xv : 0.2f*xv;
            mm[t] = fmaxf(mm[t], xv);
          }
        }
      }
      #pragma unroll
      for (int o = 1; o < 64; o <<= 1){
        #pragma unroll
        for (int t = 0; t < H; t++) mm[t] = fmaxf(mm[t], __shfl_xor(mm[t], o));
      }
      float swl[H];
      #pragma unroll
      for (int t = 0; t < H; t++) swl[t] = 0.f;
      for (int base = rs; base < re; base += 64){
        int cnt = min(64, re - base);
        int s = -1; float wgt[H];
        #pragma unroll
        for (int t = 0; t < H; t++) wgt[t] = 0.f;
        if (lane < cnt){
          int e = edge_list[base + lane];
          s = src[e];
          #pragma unroll
          for (int t = 0; t < H; t++){
            float xv = el[(size_t)s*H + t] + ern[t];
            xv = xv > 0.f ? xv : 0.2f*xv;
            wgt[t] = __expf(xv - mm[t]);
            swl[t] += wgt[t];
          }
        }
        for (int i = 0; i < cnt; i++){
          int sb = __shfl(s, i);
          if constexpr (H == 4){
            float w0=__shfl(wgt[0],i), w1=__shfl(wgt[1],i), w2=__shfl(wgt[2],i), w3=__shfl(wgt[3],i);
            float wb = (h==0)?w0:(h==1)?w1:(h==2)?w2:w3;
            float4 f = *(const float4*)&feat[(size_t)sb*256 + lane*4];
            acc[0] += f.x*wb; acc[1] += f.y*wb; acc[2] += f.z*wb; acc[3] += f.w*wb;
          } else {
            float wb = __shfl(wgt[0], i);
            acc[0] += feat[(size_t)sb*64 + lane] * wb;
          }
        }
      }
      #pragma unroll
      for (int o = 1; o < 64; o <<= 1){
        #pragma unroll
        for (int t = 0; t < H; t++) swl[t] += __shfl_xor(swl[t], o);
      }
      float ss = (H==4) ? ((h==0)?swl[0]:(h==1)?swl[1]:(h==2)?swl[2]:swl[3]) : swl[0];
      inv = 1.f / ss;
    }
  }

  if constexpr (H == 4){
    float4 o;
    o.x = acc[0]*inv + bias[lane*4+0];
    o.y = acc[1]*inv + bias[lane*4+1];
    o.z = acc[2]*inv + bias[lane*4+2];
    o.w = acc[3]*inv + bias[lane*4+3];
    if (RELU){ o.x=fmaxf(o.x,0.f); o.y=fmaxf(o.y,0.f); o.z=fmaxf(o.z,0.f); o.w=fmaxf(o.w,0.f); }
    *(float4*)&out[(size_t)n*256 + lane*4] = o;
  } else {
    float o = acc[0]*inv + bias[lane];
    if (RELU) o = fmaxf(o, 0.f);
    out[(size_t)n*64 + lane] = o;
  }
}

// ---------------- launch ----------------
extern "C" void kernel_launch(void* const* d_in, const int* in_sizes, int n_in,
                              void* d_out, int out_size, void* d_ws, size_t ws_size,
                              hipStream_t stream) {
  const float* emb = (const float*)d_in[0];
  const int*   src = (const int*)d_in[1];
  const int*   dst = (const int*)d_in[2];
  const float* W1  = (const float*)d_in[3];
  const float* al1 = (const float*)d_in[4];
  const float* ar1 = (const float*)d_in[5];
  const float* b1  = (const float*)d_in[6];
  const float* W2  = (const float*)d_in[7];
  const float* al2 = (const float*)d_in[8];
  const float* ar2 = (const float*)d_in[9];
  const float* b2  = (const float*)d_in[10];
  float* out = (float*)d_out;

  const int N = in_sizes[0] / 128;
  const int E = in_sizes[1];

  char* p = (char*)d_ws;
  auto alloc = [&](size_t bytes) -> void* {
    void* r = (void*)p; p += (bytes + 255) & ~(size_t)255; return r;
  };
  float* feat1     = (float*)alloc((size_t)N*256*4);
  float* h1        = (float*)alloc((size_t)N*256*4);
  float* feat2     = (float*)alloc((size_t)N*64*4);
  float* el1       = (float*)alloc((size_t)N*4*4);
  float* er1       = (float*)alloc((size_t)N*4*4);
  float* el2       = (float*)alloc((size_t)N*4);
  float* er2       = (float*)alloc((size_t)N*4);
  int*   deg       = (int*)alloc((size_t)N*4);
  int*   row_start = (int*)alloc((size_t)(N+1)*4);
  int*   cursor    = (int*)alloc((size_t)N*4);
  int*   edge_list = (int*)alloc((size_t)E*4);

  // CSR build (per-launch, deterministic work)
  hipMemsetAsync(deg, 0, (size_t)N*4, stream);
  k_count_deg<<<DIV_UP(E,256), 256, 0, stream>>>(dst, deg, E);
  k_scan<<<1, 1024, 0, stream>>>(deg, row_start, cursor, N);
  k_fill<<<DIV_UP(E,256), 256, 0, stream>>>(dst, cursor, edge_list, E);

  // Layer 1: feat1 = emb @ W1  [N,256]
  k_gemm<<<dim3(DIV_UP(N,64), 4), 256, 0, stream>>>(emb, W1, feat1, N, 256, 128);
  k_attn<4><<<DIV_UP(N*4,4), 256, 0, stream>>>(feat1, al1, ar1, el1, er1, N);
  k_agg<4,true><<<DIV_UP(N,4), 256, 0, stream>>>(feat1, el1, er1, row_start, edge_list,
                                                 src, b1, h1, N);
  // Layer 2: feat2 = h1 @ W2  [N,64]
  k_gemm<<<dim3(DIV_UP(N,64), 1), 256, 0, stream>>>(h1, W2, feat2, N, 64, 256);
  k_attn<1><<<DIV_UP(N,4), 256, 0, stream>>>(feat2, al2, ar2, el2, er2, N);
  k_agg<1,false><<<DIV_UP(N,4), 256, 0, stream>>>(feat2, el2, er2, row_start, edge_list,
                                                  src, b2, out, N);
}

// Round 2
// 489.045 us; speedup vs baseline: 1.0707x; 1.0707x over previous
//
#include <hip/hip_runtime.h>
#include <hip/hip_bf16.h>
#include <math.h>

#define DIV_UP(a,b) (((a)+(b)-1)/(b))

__device__ __forceinline__ float bf_lo(unsigned u){ union{unsigned x; float f;} v; v.x = u << 16; return v.f; }
__device__ __forceinline__ float bf_hi(unsigned u){ union{unsigned x; float f;} v; v.x = u & 0xffff0000u; return v.f; }
__device__ __forceinline__ unsigned short f2bf(float f){
  union{float f; unsigned u;} v; v.f = f;
  unsigned r = v.u + 0x7fff + ((v.u >> 16) & 1);   // round-nearest-even
  return (unsigned short)(r >> 16);
}

// ---------------- CSR build ----------------
__global__ void k_count_deg(const int* __restrict__ dst, int* __restrict__ deg, int E){
  int i = blockIdx.x*blockDim.x + threadIdx.x;
  if (i < E) atomicAdd(&deg[dst[i]], 1);
}

__global__ void k_scan(const int* __restrict__ deg, int* __restrict__ row_start,
                       int* __restrict__ cursor, int N){
  __shared__ int sums[1024];
  int tid = threadIdx.x;
  int chunk = (N + 1023) / 1024;
  int base = tid * chunk;
  int s = 0;
  for (int i = 0; i < chunk; i++){ int idx = base + i; if (idx < N) s += deg[idx]; }
  sums[tid] = s; __syncthreads();
  for (int off = 1; off < 1024; off <<= 1){
    int v = (tid >= off) ? sums[tid - off] : 0;
    __syncthreads();
    sums[tid] += v;
    __syncthreads();
  }
  int run = (tid == 0) ? 0 : sums[tid - 1];
  for (int i = 0; i < chunk; i++){
    int idx = base + i;
    if (idx < N){ row_start[idx] = run; cursor[idx] = run; run += deg[idx]; }
  }
  if (tid == 0) row_start[N] = sums[1023];
}

__global__ void k_fill(const int* __restrict__ dst, int* __restrict__ cursor,
                       int* __restrict__ edge_list, int E){
  int i = blockIdx.x*blockDim.x + threadIdx.x;
  if (i < E){ int p = atomicAdd(&cursor[dst[i]], 1); edge_list[p] = i; }
}

// ---------------- fp32 tiled GEMM: C[M,N] = A[M,K] @ B[K,N]; also emits bf16 copy ----------------
__global__ __launch_bounds__(256) void k_gemm(const float* __restrict__ A,
                                              const float* __restrict__ B,
                                              float* __restrict__ C,
                                              __hip_bfloat16* __restrict__ Cbf,
                                              int M, int N, int K){
  __shared__ float As[32][68];  // [k][m]
  __shared__ float Bs[32][68];  // [k][n]
  int tid = threadIdx.x;
  int tx = tid & 15, ty = tid >> 4;
  int m0 = blockIdx.x * 64, n0 = blockIdx.y * 64;
  float acc[4][4] = {};
  for (int k0 = 0; k0 < K; k0 += 32){
    #pragma unroll
    for (int i = 0; i < 2; i++){
      int q = tid + i*256;
      int row = q >> 3, c4 = q & 7;
      float4 a = make_float4(0.f,0.f,0.f,0.f);
      if (m0 + row < M) a = *(const float4*)&A[(size_t)(m0+row)*K + k0 + c4*4];
      As[c4*4+0][row] = a.x; As[c4*4+1][row] = a.y;
      As[c4*4+2][row] = a.z; As[c4*4+3][row] = a.w;
    }
    #pragma unroll
    for (int i = 0; i < 2; i++){
      int q = tid + i*256;
      int row = q >> 4, c4 = q & 15;
      float4 b = *(const float4*)&B[(size_t)(k0+row)*N + n0 + c4*4];
      *(float4*)&Bs[row][c4*4] = b;
    }
    __syncthreads();
    #pragma unroll
    for (int kk = 0; kk < 32; kk++){
      float4 av = *(const float4*)&As[kk][ty*4];
      float4 bv = *(const float4*)&Bs[kk][tx*4];
      float a_[4] = {av.x, av.y, av.z, av.w};
      float b_[4] = {bv.x, bv.y, bv.z, bv.w};
      #pragma unroll
      for (int i = 0; i < 4; i++)
        #pragma unroll
        for (int j = 0; j < 4; j++)
          acc[i][j] += a_[i] * b_[j];
    }
    __syncthreads();
  }
  #pragma unroll
  for (int i = 0; i < 4; i++){
    int r = m0 + ty*4 + i;
    if (r < M){
      *(float4*)&C[(size_t)r*N + n0 + tx*4] =
          make_float4(acc[i][0], acc[i][1], acc[i][2], acc[i][3]);
      ushort4 ub;
      ub.x = f2bf(acc[i][0]); ub.y = f2bf(acc[i][1]);
      ub.z = f2bf(acc[i][2]); ub.w = f2bf(acc[i][3]);
      *(ushort4*)&Cbf[(size_t)r*N + n0 + tx*4] = ub;
    }
  }
}

// ---------------- el/er dot products: one wave per (n,h), D=64 ----------------
template<int H>
__global__ __launch_bounds__(256) void k_attn(const float* __restrict__ feat,
      const float* __restrict__ al, const float* __restrict__ ar,
      float* __restrict__ el, float* __restrict__ er, int N){
  int w = (blockIdx.x*256 + threadIdx.x) >> 6;
  int lane = threadIdx.x & 63;
  if (w >= N*H) return;
  int n = w / H, h = w - n*H;
  float v = feat[(size_t)n*(H*64) + h*64 + lane];
  float pl = v * al[h*64 + lane];
  float pr = v * ar[h*64 + lane];
  #pragma unroll
  for (int o = 32; o; o >>= 1){ pl += __shfl_down(pl, o); pr += __shfl_down(pr, o); }
  if (lane == 0){ el[(size_t)n*H + h] = pl; er[(size_t)n*H + h] = pr; }
}

// ---------------- fused edge-softmax + aggregation (bf16 feature gather) ----------------
template<int H, bool RELU>
__global__ __launch_bounds__(256) void k_agg(const __hip_bfloat16* __restrict__ featbf,
      const float* __restrict__ el, const float* __restrict__ er,
      const int* __restrict__ row_start, const int* __restrict__ edge_list,
      const int* __restrict__ src, const float* __restrict__ bias,
      float* __restrict__ out, int N){
  constexpr int LPH = 64 / H;
  int wid  = (blockIdx.x*256 + threadIdx.x) >> 6;
  int lane = threadIdx.x & 63;
  if (wid >= N) return;
  int n = wid;
  int h = lane / LPH;
  int rs = row_start[n], re = row_start[n+1];
  int deg = re - rs;

  float ern[H];
  #pragma unroll
  for (int t = 0; t < H; t++) ern[t] = er[(size_t)n*H + t];

  float acc[H];
  #pragma unroll
  for (int t = 0; t < H; t++) acc[t] = 0.f;
  float inv = 0.f;

  const unsigned* featu = (const unsigned*)featbf;

  if (deg > 0){
    if (deg <= 64){
      int s = -1;
      float x[H];
      #pragma unroll
      for (int t = 0; t < H; t++) x[t] = -INFINITY;
      if (lane < deg){
        int e = edge_list[rs + lane];
        s = src[e];
        #pragma unroll
        for (int t = 0; t < H; t++){
          float xv = el[(size_t)s*H + t] + ern[t];
          x[t] = xv > 0.f ? xv : 0.2f*xv;
        }
      }
      float mm[H];
      #pragma unroll
      for (int t = 0; t < H; t++) mm[t] = x[t];
      #pragma unroll
      for (int o = 1; o < 64; o <<= 1){
        #pragma unroll
        for (int t = 0; t < H; t++) mm[t] = fmaxf(mm[t], __shfl_xor(mm[t], o));
      }
      float wgt[H];
      #pragma unroll
      for (int t = 0; t < H; t++) wgt[t] = (lane < deg) ? __expf(x[t]-mm[t]) : 0.f;
      float sw[H];
      #pragma unroll
      for (int t = 0; t < H; t++) sw[t] = wgt[t];
      #pragma unroll
      for (int o = 1; o < 64; o <<= 1){
        #pragma unroll
        for (int t = 0; t < H; t++) sw[t] += __shfl_xor(sw[t], o);
      }
      for (int i = 0; i < deg; i++){
        int sb = __shfl(s, i);
        if constexpr (H == 4){
          float w0=__shfl(wgt[0],i), w1=__shfl(wgt[1],i), w2=__shfl(wgt[2],i), w3=__shfl(wgt[3],i);
          float wb = (h==0)?w0:(h==1)?w1:(h==2)?w2:w3;
          uint2 u = *(const uint2*)&featu[(size_t)sb*128 + lane*2]; // 4 bf16
          acc[0] += bf_lo(u.x)*wb; acc[1] += bf_hi(u.x)*wb;
          acc[2] += bf_lo(u.y)*wb; acc[3] += bf_hi(u.y)*wb;
        } else {
          float wb = __shfl(wgt[0], i);
          unsigned u = featu[(size_t)sb*32 + (lane>>1)];            // 2 bf16
          acc[0] += ((lane & 1) ? bf_hi(u) : bf_lo(u)) * wb;
        }
      }
      float ss = (H==4) ? ((h==0)?sw[0]:(h==1)?sw[1]:(h==2)?sw[2]:sw[3]) : sw[0];
      inv = 1.f / ss;
    } else {
      // chunked slow path (deg > 64)
      float mm[H];
      #pragma unroll
      for (int t = 0; t < H; t++) mm[t] = -INFINITY;
      for (int base = rs; base < re; base += 64){
        int cnt = min(64, re - base);
        if (lane < cnt){
          int e = edge_list[base + lane];
          int s = src[e];
          #pragma unroll
          for (int t = 0; t < H; t++){
            float xv = el[(size_t)s*H + t] + ern[t];
            xv = xv > 0.f ? xv : 0.2f*xv;
            mm[t] = fmaxf(mm[t], xv);
          }
        }
      }
      #pragma unroll
      for (int o = 1; o < 64; o <<= 1){
        #pragma unroll
        for (int t = 0; t < H; t++) mm[t] = fmaxf(mm[t], __shfl_xor(mm[t], o));
      }
      float swl[H];
      #pragma unroll
      for (int t = 0; t < H; t++) swl[t] = 0.f;
      for (int base = rs; base < re; base += 64){
        int cnt = min(64, re - base);
        int s = -1; float wgt[H];
        #pragma unroll
        for (int t = 0; t < H; t++) wgt[t] = 0.f;
        if (lane < cnt){
          int e = edge_list[base + lane];
          s = src[e];
          #pragma unroll
          for (int t = 0; t < H; t++){
            float xv = el[(size_t)s*H + t] + ern[t];
            xv = xv > 0.f ? xv : 0.2f*xv;
            wgt[t] = __expf(xv - mm[t]);
            swl[t] += wgt[t];
          }
        }
        for (int i = 0; i < cnt; i++){
          int sb = __shfl(s, i);
          if constexpr (H == 4){
            float w0=__shfl(wgt[0],i), w1=__shfl(wgt[1],i), w2=__shfl(wgt[2],i), w3=__shfl(wgt[3],i);
            float wb = (h==0)?w0:(h==1)?w1:(h==2)?w2:w3;
            uint2 u = *(const uint2*)&featu[(size_t)sb*128 + lane*2];
            acc[0] += bf_lo(u.x)*wb; acc[1] += bf_hi(u.x)*wb;
            acc[2] += bf_lo(u.y)*wb; acc[3] += bf_hi(u.y)*wb;
          } else {
            float wb = __shfl(wgt[0], i);
            unsigned u = featu[(size_t)sb*32 + (lane>>1)];
            acc[0] += ((lane & 1) ? bf_hi(u) : bf_lo(u)) * wb;
          }
        }
      }
      #pragma unroll
      for (int o = 1; o < 64; o <<= 1){
        #pragma unroll
        for (int t = 0; t < H; t++) swl[t] += __shfl_xor(swl[t], o);
      }
      float ss = (H==4) ? ((h==0)?swl[0]:(h==1)?swl[1]:(h==2)?swl[2]:swl[3]) : swl[0];
      inv = 1.f / ss;
    }
  }

  if constexpr (H == 4){
    float4 o;
    o.x = acc[0]*inv + bias[lane*4+0];
    o.y = acc[1]*inv + bias[lane*4+1];
    o.z = acc[2]*inv + bias[lane*4+2];
    o.w = acc[3]*inv + bias[lane*4+3];
    if (RELU){ o.x=fmaxf(o.x,0.f); o.y=fmaxf(o.y,0.f); o.z=fmaxf(o.z,0.f); o.w=fmaxf(o.w,0.f); }
    *(float4*)&out[(size_t)n*256 + lane*4] = o;
  } else {
    float o = acc[0]*inv + bias[lane];
    if (RELU) o = fmaxf(o, 0.f);
    out[(size_t)n*64 + lane] = o;
  }
}

// ---------------- launch ----------------
extern "C" void kernel_launch(void* const* d_in, const int* in_sizes, int n_in,
                              void* d_out, int out_size, void* d_ws, size_t ws_size,
                              hipStream_t stream) {
  const float* emb = (const float*)d_in[0];
  const int*   src = (const int*)d_in[1];
  const int*   dst = (const int*)d_in[2];
  const float* W1  = (const float*)d_in[3];
  const float* al1 = (const float*)d_in[4];
  const float* ar1 = (const float*)d_in[5];
  const float* b1  = (const float*)d_in[6];
  const float* W2  = (const float*)d_in[7];
  const float* al2 = (const float*)d_in[8];
  const float* ar2 = (const float*)d_in[9];
  const float* b2  = (const float*)d_in[10];
  float* out = (float*)d_out;

  const int N = in_sizes[0] / 128;
  const int E = in_sizes[1];

  char* p = (char*)d_ws;
  auto alloc = [&](size_t bytes) -> void* {
    void* r = (void*)p; p += (bytes + 255) & ~(size_t)255; return r;
  };
  float* feat1            = (float*)alloc((size_t)N*256*4);
  __hip_bfloat16* feat1b  = (__hip_bfloat16*)alloc((size_t)N*256*2);
  float* h1               = (float*)alloc((size_t)N*256*4);
  __hip_bfloat16* h1b     = (__hip_bfloat16*)alloc((size_t)N*256*2); // unused gather, needed as Cbf slot
  float* feat2            = (float*)alloc((size_t)N*64*4);
  __hip_bfloat16* feat2b  = (__hip_bfloat16*)alloc((size_t)N*64*2);
  float* el1              = (float*)alloc((size_t)N*4*4);
  float* er1              = (float*)alloc((size_t)N*4*4);
  float* el2              = (float*)alloc((size_t)N*4);
  float* er2              = (float*)alloc((size_t)N*4);
  int*   deg              = (int*)alloc((size_t)N*4);
  int*   row_start        = (int*)alloc((size_t)(N+1)*4);
  int*   cursor           = (int*)alloc((size_t)N*4);
  int*   edge_list        = (int*)alloc((size_t)E*4);

  // CSR build (per-launch, deterministic work)
  hipMemsetAsync(deg, 0, (size_t)N*4, stream);
  k_count_deg<<<DIV_UP(E,256), 256, 0, stream>>>(dst, deg, E);
  k_scan<<<1, 1024, 0, stream>>>(deg, row_start, cursor, N);
  k_fill<<<DIV_UP(E,256), 256, 0, stream>>>(dst, cursor, edge_list, E);

  // Layer 1
  k_gemm<<<dim3(DIV_UP(N,64), 4), 256, 0, stream>>>(emb, W1, feat1, feat1b, N, 256, 128);
  k_attn<4><<<DIV_UP(N*4,4), 256, 0, stream>>>(feat1, al1, ar1, el1, er1, N);
  k_agg<4,true><<<DIV_UP(N,4), 256, 0, stream>>>(feat1b, el1, er1, row_start, edge_list,
                                                 src, b1, h1, N);
  // Layer 2
  k_gemm<<<dim3(DIV_UP(N,64), 1), 256, 0, stream>>>(h1, W2, feat2, feat2b, N, 64, 256);
  k_attn<1><<<DIV_UP(N,4), 256, 0, stream>>>(feat2, al2, ar2, el2, er2, N);
  k_agg<1,false><<<DIV_UP(N,4), 256, 0, stream>>>(feat2b, el2, er2, row_start, edge_list,
                                                  src, b2, out, N);
}

// Round 3
// 371.551 us; speedup vs baseline: 1.4092x; 1.3162x over previous
//
#include <hip/hip_runtime.h>
#include <hip/hip_bf16.h>
#include <math.h>

#define DIV_UP(a,b) (((a)+(b)-1)/(b))

__device__ __forceinline__ float bf_lo(unsigned u){ union{unsigned x; float f;} v; v.x = u << 16; return v.f; }
__device__ __forceinline__ float bf_hi(unsigned u){ union{unsigned x; float f;} v; v.x = u & 0xffff0000u; return v.f; }
__device__ __forceinline__ unsigned short f2bf(float f){
  union{float f; unsigned u;} v; v.f = f;
  unsigned r = v.u + 0x7fff + ((v.u >> 16) & 1);   // round-nearest-even
  return (unsigned short)(r >> 16);
}

// ---------------- CSR build ----------------
__global__ void k_count_deg(const int* __restrict__ dst, int* __restrict__ deg, int E){
  int i = blockIdx.x*blockDim.x + threadIdx.x;
  if (i < E) atomicAdd(&deg[dst[i]], 1);
}

// Phase 1: per-block (1024 elems) sums. 256 threads, 4 elems/thread.
__global__ __launch_bounds__(256) void k_scan1(const int* __restrict__ deg,
                                               int* __restrict__ blocksum, int N){
  int b = blockIdx.x;
  int base = b*1024 + threadIdx.x*4;
  int s = 0;
  if (base + 3 < N){
    int4 v = *(const int4*)&deg[base];
    s = v.x + v.y + v.z + v.w;
  } else {
    for (int i = 0; i < 4; i++){ int idx = base + i; if (idx < N) s += deg[idx]; }
  }
  #pragma unroll
  for (int o = 32; o; o >>= 1) s += __shfl_down(s, o);
  __shared__ int ws[4];
  int wid = threadIdx.x >> 6, lane = threadIdx.x & 63;
  if (lane == 0) ws[wid] = s;
  __syncthreads();
  if (threadIdx.x == 0) blocksum[b] = ws[0] + ws[1] + ws[2] + ws[3];
}

// Phase 2: one wave scans block sums (exclusive, in place). nb up to a few thousand.
__global__ void k_scan2(int* __restrict__ blocksum, int nb){
  int lane = threadIdx.x;  // 64 threads
  int carry = 0;
  for (int base = 0; base < nb; base += 64){
    int idx = base + lane;
    int orig = (idx < nb) ? blocksum[idx] : 0;
    int v = orig;
    #pragma unroll
    for (int o = 1; o < 64; o <<= 1){ int t = __shfl_up(v, o); if (lane >= o) v += t; }
    if (idx < nb) blocksum[idx] = carry + v - orig;   // exclusive
    carry += __shfl(v, 63);
  }
}

// Phase 3: local exclusive scan + block offset -> row_start, cursor.
__global__ __launch_bounds__(256) void k_scan3(const int* __restrict__ deg,
                                               const int* __restrict__ blockoff,
                                               int* __restrict__ row_start,
                                               int* __restrict__ cursor, int N){
  int b = blockIdx.x;
  int base = b*1024 + threadIdx.x*4;
  int v[4];
  #pragma unroll
  for (int i = 0; i < 4; i++){ int idx = base + i; v[i] = (idx < N) ? deg[idx] : 0; }
  int s = v[0] + v[1] + v[2] + v[3];
  int lane = threadIdx.x & 63, wid = threadIdx.x >> 6;
  int inc = s;
  #pragma unroll
  for (int o = 1; o < 64; o <<= 1){ int t = __shfl_up(inc, o); if (lane >= o) inc += t; }
  __shared__ int wsum[4];
  if (lane == 63) wsum[wid] = inc;
  __syncthreads();
  int woff = 0;
  #pragma unroll
  for (int i = 0; i < 4; i++) if (i < wid) woff += wsum[i];
  int run = blockoff[b] + woff + inc - s;   // exclusive prefix of this thread's first item
  #pragma unroll
  for (int i = 0; i < 4; i++){
    int idx = base + i;
    if (idx < N){ row_start[idx] = run; cursor[idx] = run; run += v[i]; }
  }
  if (base < N && base + 4 >= N) row_start[N] = run;  // thread holding last element
}

__global__ void k_fill(const int* __restrict__ dst, int* __restrict__ cursor,
                       int* __restrict__ edge_list, int E){
  int i = blockIdx.x*blockDim.x + threadIdx.x;
  if (i < E){ int p = atomicAdd(&cursor[dst[i]], 1); edge_list[p] = i; }
}

// ---------------- fp32 tiled GEMM: C[M,N] = A[M,K] @ B[K,N]; also emits bf16 copy ----------------
__global__ __launch_bounds__(256) void k_gemm(const float* __restrict__ A,
                                              const float* __restrict__ B,
                                              float* __restrict__ C,
                                              __hip_bfloat16* __restrict__ Cbf,
                                              int M, int N, int K){
  __shared__ float As[32][68];  // [k][m]
  __shared__ float Bs[32][68];  // [k][n]
  int tid = threadIdx.x;
  int tx = tid & 15, ty = tid >> 4;
  int m0 = blockIdx.x * 64, n0 = blockIdx.y * 64;
  float acc[4][4] = {};
  for (int k0 = 0; k0 < K; k0 += 32){
    #pragma unroll
    for (int i = 0; i < 2; i++){
      int q = tid + i*256;
      int row = q >> 3, c4 = q & 7;
      float4 a = make_float4(0.f,0.f,0.f,0.f);
      if (m0 + row < M) a = *(const float4*)&A[(size_t)(m0+row)*K + k0 + c4*4];
      As[c4*4+0][row] = a.x; As[c4*4+1][row] = a.y;
      As[c4*4+2][row] = a.z; As[c4*4+3][row] = a.w;
    }
    #pragma unroll
    for (int i = 0; i < 2; i++){
      int q = tid + i*256;
      int row = q >> 4, c4 = q & 15;
      float4 b = *(const float4*)&B[(size_t)(k0+row)*N + n0 + c4*4];
      *(float4*)&Bs[row][c4*4] = b;
    }
    __syncthreads();
    #pragma unroll
    for (int kk = 0; kk < 32; kk++){
      float4 av = *(const float4*)&As[kk][ty*4];
      float4 bv = *(const float4*)&Bs[kk][tx*4];
      float a_[4] = {av.x, av.y, av.z, av.w};
      float b_[4] = {bv.x, bv.y, bv.z, bv.w};
      #pragma unroll
      for (int i = 0; i < 4; i++)
        #pragma unroll
        for (int j = 0; j < 4; j++)
          acc[i][j] += a_[i] * b_[j];
    }
    __syncthreads();
  }
  #pragma unroll
  for (int i = 0; i < 4; i++){
    int r = m0 + ty*4 + i;
    if (r < M){
      *(float4*)&C[(size_t)r*N + n0 + tx*4] =
          make_float4(acc[i][0], acc[i][1], acc[i][2], acc[i][3]);
      ushort4 ub;
      ub.x = f2bf(acc[i][0]); ub.y = f2bf(acc[i][1]);
      ub.z = f2bf(acc[i][2]); ub.w = f2bf(acc[i][3]);
      *(ushort4*)&Cbf[(size_t)r*N + n0 + tx*4] = ub;
    }
  }
}

// ---------------- el/er dot products: one wave per (n,h), D=64 ----------------
template<int H>
__global__ __launch_bounds__(256) void k_attn(const float* __restrict__ feat,
      const float* __restrict__ al, const float* __restrict__ ar,
      float* __restrict__ el, float* __restrict__ er, int N){
  int w = (blockIdx.x*256 + threadIdx.x) >> 6;
  int lane = threadIdx.x & 63;
  if (w >= N*H) return;
  int n = w / H, h = w - n*H;
  float v = feat[(size_t)n*(H*64) + h*64 + lane];
  float pl = v * al[h*64 + lane];
  float pr = v * ar[h*64 + lane];
  #pragma unroll
  for (int o = 32; o; o >>= 1){ pl += __shfl_down(pl, o); pr += __shfl_down(pr, o); }
  if (lane == 0){ el[(size_t)n*H + h] = pl; er[(size_t)n*H + h] = pr; }
}

// ---------------- fused edge-softmax + aggregation (bf16 feature gather) ----------------
template<int H, bool RELU>
__global__ __launch_bounds__(256) void k_agg(const __hip_bfloat16* __restrict__ featbf,
      const float* __restrict__ el, const float* __restrict__ er,
      const int* __restrict__ row_start, const int* __restrict__ edge_list,
      const int* __restrict__ src, const float* __restrict__ bias,
      float* __restrict__ out, int N){
  constexpr int LPH = 64 / H;
  int wid  = (blockIdx.x*256 + threadIdx.x) >> 6;
  int lane = threadIdx.x & 63;
  if (wid >= N) return;
  int n = wid;
  int h = lane / LPH;
  int rs = row_start[n], re = row_start[n+1];
  int deg = re - rs;

  float ern[H];
  #pragma unroll
  for (int t = 0; t < H; t++) ern[t] = er[(size_t)n*H + t];

  float acc[H];
  #pragma unroll
  for (int t = 0; t < H; t++) acc[t] = 0.f;
  float inv = 0.f;

  const unsigned* featu = (const unsigned*)featbf;

  if (deg > 0){
    if (deg <= 64){
      int s = -1;
      float x[H];
      #pragma unroll
      for (int t = 0; t < H; t++) x[t] = -INFINITY;
      if (lane < deg){
        int e = edge_list[rs + lane];
        s = src[e];
        #pragma unroll
        for (int t = 0; t < H; t++){
          float xv = el[(size_t)s*H + t] + ern[t];
          x[t] = xv > 0.f ? xv : 0.2f*xv;
        }
      }
      float mm[H];
      #pragma unroll
      for (int t = 0; t < H; t++) mm[t] = x[t];
      #pragma unroll
      for (int o = 1; o < 64; o <<= 1){
        #pragma unroll
        for (int t = 0; t < H; t++) mm[t] = fmaxf(mm[t], __shfl_xor(mm[t], o));
      }
      float wgt[H];
      #pragma unroll
      for (int t = 0; t < H; t++) wgt[t] = (lane < deg) ? __expf(x[t]-mm[t]) : 0.f;
      float sw[H];
      #pragma unroll
      for (int t = 0; t < H; t++) sw[t] = wgt[t];
      #pragma unroll
      for (int o = 1; o < 64; o <<= 1){
        #pragma unroll
        for (int t = 0; t < H; t++) sw[t] += __shfl_xor(sw[t], o);
      }
      for (int i = 0; i < deg; i++){
        int sb = __shfl(s, i);
        if constexpr (H == 4){
          float w0=__shfl(wgt[0],i), w1=__shfl(wgt[1],i), w2=__shfl(wgt[2],i), w3=__shfl(wgt[3],i);
          float wb = (h==0)?w0:(h==1)?w1:(h==2)?w2:w3;
          uint2 u = *(const uint2*)&featu[(size_t)sb*128 + lane*2]; // 4 bf16
          acc[0] += bf_lo(u.x)*wb; acc[1] += bf_hi(u.x)*wb;
          acc[2] += bf_lo(u.y)*wb; acc[3] += bf_hi(u.y)*wb;
        } else {
          float wb = __shfl(wgt[0], i);
          unsigned u = featu[(size_t)sb*32 + (lane>>1)];            // 2 bf16
          acc[0] += ((lane & 1) ? bf_hi(u) : bf_lo(u)) * wb;
        }
      }
      float ss = (H==4) ? ((h==0)?sw[0]:(h==1)?sw[1]:(h==2)?sw[2]:sw[3]) : sw[0];
      inv = 1.f / ss;
    } else {
      // chunked slow path (deg > 64)
      float mm[H];
      #pragma unroll
      for (int t = 0; t < H; t++) mm[t] = -INFINITY;
      for (int base = rs; base < re; base += 64){
        int cnt = min(64, re - base);
        if (lane < cnt){
          int e = edge_list[base + lane];
          int s = src[e];
          #pragma unroll
          for (int t = 0; t < H; t++){
            float xv = el[(size_t)s*H + t] + ern[t];
            xv = xv > 0.f ? xv : 0.2f*xv;
            mm[t] = fmaxf(mm[t], xv);
          }
        }
      }
      #pragma unroll
      for (int o = 1; o < 64; o <<= 1){
        #pragma unroll
        for (int t = 0; t < H; t++) mm[t] = fmaxf(mm[t], __shfl_xor(mm[t], o));
      }
      float swl[H];
      #pragma unroll
      for (int t = 0; t < H; t++) swl[t] = 0.f;
      for (int base = rs; base < re; base += 64){
        int cnt = min(64, re - base);
        int s = -1; float wgt[H];
        #pragma unroll
        for (int t = 0; t < H; t++) wgt[t] = 0.f;
        if (lane < cnt){
          int e = edge_list[base + lane];
          s = src[e];
          #pragma unroll
          for (int t = 0; t < H; t++){
            float xv = el[(size_t)s*H + t] + ern[t];
            xv = xv > 0.f ? xv : 0.2f*xv;
            wgt[t] = __expf(xv - mm[t]);
            swl[t] += wgt[t];
          }
        }
        for (int i = 0; i < cnt; i++){
          int sb = __shfl(s, i);
          if constexpr (H == 4){
            float w0=__shfl(wgt[0],i), w1=__shfl(wgt[1],i), w2=__shfl(wgt[2],i), w3=__shfl(wgt[3],i);
            float wb = (h==0)?w0:(h==1)?w1:(h==2)?w2:w3;
            uint2 u = *(const uint2*)&featu[(size_t)sb*128 + lane*2];
            acc[0] += bf_lo(u.x)*wb; acc[1] += bf_hi(u.x)*wb;
            acc[2] += bf_lo(u.y)*wb; acc[3] += bf_hi(u.y)*wb;
          } else {
            float wb = __shfl(wgt[0], i);
            unsigned u = featu[(size_t)sb*32 + (lane>>1)];
            acc[0] += ((lane & 1) ? bf_hi(u) : bf_lo(u)) * wb;
          }
        }
      }
      #pragma unroll
      for (int o = 1; o < 64; o <<= 1){
        #pragma unroll
        for (int t = 0; t < H; t++) swl[t] += __shfl_xor(swl[t], o);
      }
      float ss = (H==4) ? ((h==0)?swl[0]:(h==1)?swl[1]:(h==2)?swl[2]:swl[3]) : swl[0];
      inv = 1.f / ss;
    }
  }

  if constexpr (H == 4){
    float4 o;
    o.x = acc[0]*inv + bias[lane*4+0];
    o.y = acc[1]*inv + bias[lane*4+1];
    o.z = acc[2]*inv + bias[lane*4+2];
    o.w = acc[3]*inv + bias[lane*4+3];
    if (RELU){ o.x=fmaxf(o.x,0.f); o.y=fmaxf(o.y,0.f); o.z=fmaxf(o.z,0.f); o.w=fmaxf(o.w,0.f); }
    *(float4*)&out[(size_t)n*256 + lane*4] = o;
  } else {
    float o = acc[0]*inv + bias[lane];
    if (RELU) o = fmaxf(o, 0.f);
    out[(size_t)n*64 + lane] = o;
  }
}

// ---------------- launch ----------------
extern "C" void kernel_launch(void* const* d_in, const int* in_sizes, int n_in,
                              void* d_out, int out_size, void* d_ws, size_t ws_size,
                              hipStream_t stream) {
  const float* emb = (const float*)d_in[0];
  const int*   src = (const int*)d_in[1];
  const int*   dst = (const int*)d_in[2];
  const float* W1  = (const float*)d_in[3];
  const float* al1 = (const float*)d_in[4];
  const float* ar1 = (const float*)d_in[5];
  const float* b1  = (const float*)d_in[6];
  const float* W2  = (const float*)d_in[7];
  const float* al2 = (const float*)d_in[8];
  const float* ar2 = (const float*)d_in[9];
  const float* b2  = (const float*)d_in[10];
  float* out = (float*)d_out;

  const int N = in_sizes[0] / 128;
  const int E = in_sizes[1];

  char* p = (char*)d_ws;
  auto alloc = [&](size_t bytes) -> void* {
    void* r = (void*)p; p += (bytes + 255) & ~(size_t)255; return r;
  };
  float* feat1            = (float*)alloc((size_t)N*256*4);
  __hip_bfloat16* feat1b  = (__hip_bfloat16*)alloc((size_t)N*256*2);
  float* h1               = (float*)alloc((size_t)N*256*4);
  __hip_bfloat16* h1b     = (__hip_bfloat16*)alloc((size_t)N*256*2);
  float* feat2            = (float*)alloc((size_t)N*64*4);
  __hip_bfloat16* feat2b  = (__hip_bfloat16*)alloc((size_t)N*64*2);
  float* el1              = (float*)alloc((size_t)N*4*4);
  float* er1              = (float*)alloc((size_t)N*4*4);
  float* el2              = (float*)alloc((size_t)N*4);
  float* er2              = (float*)alloc((size_t)N*4);
  int*   deg              = (int*)alloc((size_t)N*4);
  int*   row_start        = (int*)alloc((size_t)(N+1)*4);
  int*   cursor           = (int*)alloc((size_t)N*4);
  int*   blocksum         = (int*)alloc((size_t)DIV_UP(N,1024)*4);
  int*   edge_list        = (int*)alloc((size_t)E*4);

  const int nb = DIV_UP(N, 1024);

  // CSR build (per-launch, deterministic work)
  hipMemsetAsync(deg, 0, (size_t)N*4, stream);
  k_count_deg<<<DIV_UP(E,256), 256, 0, stream>>>(dst, deg, E);
  k_scan1<<<nb, 256, 0, stream>>>(deg, blocksum, N);
  k_scan2<<<1, 64, 0, stream>>>(blocksum, nb);
  k_scan3<<<nb, 256, 0, stream>>>(deg, blocksum, row_start, cursor, N);
  k_fill<<<DIV_UP(E,256), 256, 0, stream>>>(dst, cursor, edge_list, E);

  // Layer 1
  k_gemm<<<dim3(DIV_UP(N,64), 4), 256, 0, stream>>>(emb, W1, feat1, feat1b, N, 256, 128);
  k_attn<4><<<DIV_UP(N*4,4), 256, 0, stream>>>(feat1, al1, ar1, el1, er1, N);
  k_agg<4,true><<<DIV_UP(N,4), 256, 0, stream>>>(feat1b, el1, er1, row_start, edge_list,
                                                 src, b1, h1, N);
  // Layer 2
  k_gemm<<<dim3(DIV_UP(N,64), 1), 256, 0, stream>>>(h1, W2, feat2, feat2b, N, 64, 256);
  k_attn<1><<<DIV_UP(N,4), 256, 0, stream>>>(feat2, al2, ar2, el2, er2, N);
  k_agg<1,false><<<DIV_UP(N,4), 256, 0, stream>>>(feat2b, el2, er2, row_start, edge_list,
                                                  src, b2, out, N);
}

// Round 4
// 283.184 us; speedup vs baseline: 1.8490x; 1.3120x over previous
//
#include <hip/hip_runtime.h>
#include <hip/hip_bf16.h>
#include <math.h>

#define DIV_UP(a,b) (((a)+(b)-1)/(b))

__device__ __forceinline__ float bf_lo(unsigned u){ union{unsigned x; float f;} v; v.x = u << 16; return v.f; }
__device__ __forceinline__ float bf_hi(unsigned u){ union{unsigned x; float f;} v; v.x = u & 0xffff0000u; return v.f; }
__device__ __forceinline__ unsigned short f2bf(float f){
  union{float f; unsigned u;} v; v.f = f;
  unsigned r = v.u + 0x7fff + ((v.u >> 16) & 1);   // round-nearest-even
  return (unsigned short)(r >> 16);
}
__device__ __forceinline__ unsigned packbf(float a, float b){
  return (unsigned)f2bf(a) | ((unsigned)f2bf(b) << 16);
}

// ---------------- CSR build ----------------
__global__ void k_count_deg(const int* __restrict__ dst, int* __restrict__ deg, int E){
  int i = blockIdx.x*blockDim.x + threadIdx.x;
  if (i < E) atomicAdd(&deg[dst[i]], 1);
}

__global__ __launch_bounds__(256) void k_scan1(const int* __restrict__ deg,
                                               int* __restrict__ blocksum, int N){
  int b = blockIdx.x;
  int base = b*1024 + threadIdx.x*4;
  int s = 0;
  if (base + 3 < N){
    int4 v = *(const int4*)&deg[base];
    s = v.x + v.y + v.z + v.w;
  } else {
    for (int i = 0; i < 4; i++){ int idx = base + i; if (idx < N) s += deg[idx]; }
  }
  #pragma unroll
  for (int o = 32; o; o >>= 1) s += __shfl_down(s, o);
  __shared__ int ws[4];
  int wid = threadIdx.x >> 6, lane = threadIdx.x & 63;
  if (lane == 0) ws[wid] = s;
  __syncthreads();
  if (threadIdx.x == 0) blocksum[b] = ws[0] + ws[1] + ws[2] + ws[3];
}

__global__ void k_scan2(int* __restrict__ blocksum, int nb){
  int lane = threadIdx.x;  // 64 threads
  int carry = 0;
  for (int base = 0; base < nb; base += 64){
    int idx = base + lane;
    int orig = (idx < nb) ? blocksum[idx] : 0;
    int v = orig;
    #pragma unroll
    for (int o = 1; o < 64; o <<= 1){ int t = __shfl_up(v, o); if (lane >= o) v += t; }
    if (idx < nb) blocksum[idx] = carry + v - orig;   // exclusive
    carry += __shfl(v, 63);
  }
}

__global__ __launch_bounds__(256) void k_scan3(const int* __restrict__ deg,
                                               const int* __restrict__ blockoff,
                                               int* __restrict__ row_start,
                                               int* __restrict__ cursor, int N){
  int b = blockIdx.x;
  int base = b*1024 + threadIdx.x*4;
  int v[4];
  #pragma unroll
  for (int i = 0; i < 4; i++){ int idx = base + i; v[i] = (idx < N) ? deg[idx] : 0; }
  int s = v[0] + v[1] + v[2] + v[3];
  int lane = threadIdx.x & 63, wid = threadIdx.x >> 6;
  int inc = s;
  #pragma unroll
  for (int o = 1; o < 64; o <<= 1){ int t = __shfl_up(inc, o); if (lane >= o) inc += t; }
  __shared__ int wsum[4];
  if (lane == 63) wsum[wid] = inc;
  __syncthreads();
  int woff = 0;
  #pragma unroll
  for (int i = 0; i < 4; i++) if (i < wid) woff += wsum[i];
  int run = blockoff[b] + woff + inc - s;
  #pragma unroll
  for (int i = 0; i < 4; i++){
    int idx = base + i;
    if (idx < N){ row_start[idx] = run; cursor[idx] = run; run += v[i]; }
  }
  if (base < N && base + 4 >= N) row_start[N] = run;
}

// fill: store SRC NODE ID directly in CSR order (edge id never needed)
__global__ void k_fill(const int* __restrict__ dst, const int* __restrict__ src,
                       int* __restrict__ cursor, int* __restrict__ srcp, int E){
  int i = blockIdx.x*blockDim.x + threadIdx.x;
  if (i < E){ int p = atomicAdd(&cursor[dst[i]], 1); srcp[p] = src[i]; }
}

// ---------------- tiled GEMM with fused el/er epilogue ----------------
// C[M,N] = A[M,K] @ B[K,N].  N-tile 64 == one head's dims exactly (head = blockIdx.y).
// Emits bf16 C only, plus el[r,H]/er[r,H] = sum_d C[r, head*64+d] * al/ar[head*64+d].
template<int H, bool ABF>
__global__ __launch_bounds__(256) void k_gemm(const void* __restrict__ Av,
                                              const float* __restrict__ B,
                                              __hip_bfloat16* __restrict__ Cbf,
                                              const float* __restrict__ al,
                                              const float* __restrict__ ar,
                                              float* __restrict__ el,
                                              float* __restrict__ er,
                                              int M, int N, int K){
  __shared__ float As[32][68];  // [k][m]
  __shared__ float Bs[32][68];  // [k][n]
  int tid = threadIdx.x;
  int tx = tid & 15, ty = tid >> 4;
  int m0 = blockIdx.x * 64, n0 = blockIdx.y * 64;
  int by = blockIdx.y;
  float acc[4][4] = {};
  for (int k0 = 0; k0 < K; k0 += 32){
    if constexpr (!ABF){
      const float* A = (const float*)Av;
      #pragma unroll
      for (int i = 0; i < 2; i++){
        int q = tid + i*256;
        int row = q >> 3, c4 = q & 7;
        float4 a = make_float4(0.f,0.f,0.f,0.f);
        if (m0 + row < M) a = *(const float4*)&A[(size_t)(m0+row)*K + k0 + c4*4];
        As[c4*4+0][row] = a.x; As[c4*4+1][row] = a.y;
        As[c4*4+2][row] = a.z; As[c4*4+3][row] = a.w;
      }
    } else {
      const __hip_bfloat16* A = (const __hip_bfloat16*)Av;
      int row = tid >> 2, c8 = tid & 3;   // 64 rows x 4 chunks of 8 bf16 = 32 cols
      uint4 u = make_uint4(0,0,0,0);
      if (m0 + row < M) u = *(const uint4*)&A[(size_t)(m0+row)*K + k0 + c8*8];
      As[c8*8+0][row] = bf_lo(u.x); As[c8*8+1][row] = bf_hi(u.x);
      As[c8*8+2][row] = bf_lo(u.y); As[c8*8+3][row] = bf_hi(u.y);
      As[c8*8+4][row] = bf_lo(u.z); As[c8*8+5][row] = bf_hi(u.z);
      As[c8*8+6][row] = bf_lo(u.w); As[c8*8+7][row] = bf_hi(u.w);
    }
    #pragma unroll
    for (int i = 0; i < 2; i++){
      int q = tid + i*256;
      int row = q >> 4, c4 = q & 15;
      float4 b = *(const float4*)&B[(size_t)(k0+row)*N + n0 + c4*4];
      *(float4*)&Bs[row][c4*4] = b;
    }
    __syncthreads();
    #pragma unroll
    for (int kk = 0; kk < 32; kk++){
      float4 av = *(const float4*)&As[kk][ty*4];
      float4 bv = *(const float4*)&Bs[kk][tx*4];
      float a_[4] = {av.x, av.y, av.z, av.w};
      float b_[4] = {bv.x, bv.y, bv.z, bv.w};
      #pragma unroll
      for (int i = 0; i < 4; i++)
        #pragma unroll
        for (int j = 0; j < 4; j++)
          acc[i][j] += a_[i] * b_[j];
    }
    __syncthreads();
  }
  // attn vectors for this head, this thread's 4 cols
  float4 alv = *(const float4*)&al[by*64 + tx*4];
  float4 arv = *(const float4*)&ar[by*64 + tx*4];
  #pragma unroll
  for (int i = 0; i < 4; i++){
    int r = m0 + ty*4 + i;
    float pl = acc[i][0]*alv.x + acc[i][1]*alv.y + acc[i][2]*alv.z + acc[i][3]*alv.w;
    float pr = acc[i][0]*arv.x + acc[i][1]*arv.y + acc[i][2]*arv.z + acc[i][3]*arv.w;
    #pragma unroll
    for (int o = 1; o < 16; o <<= 1){ pl += __shfl_xor(pl, o); pr += __shfl_xor(pr, o); }
    if (r < M){
      ushort4 ub;
      ub.x = f2bf(acc[i][0]); ub.y = f2bf(acc[i][1]);
      ub.z = f2bf(acc[i][2]); ub.w = f2bf(acc[i][3]);
      *(ushort4*)&Cbf[(size_t)r*N + n0 + tx*4] = ub;
      if (tx == 0){ el[(size_t)r*H + by] = pl; er[(size_t)r*H + by] = pr; }
    }
  }
}

// ---------------- fused edge-softmax + aggregation, H=4 (layer 1) ----------------
// Wave per node. 4 groups x 16 lanes: group g handles edge i*4+g; lane j reads
// 32B (16 dims) of the 512B bf16 feature row. Weights staged in LDS per chunk.
__global__ __launch_bounds__(256) void k_agg4(const uint4* __restrict__ featq, // [N][32] uint4
      const float4* __restrict__ el4, const float4* __restrict__ er4,
      const int* __restrict__ row_start, const int* __restrict__ srcp,
      const float* __restrict__ bias, __hip_bfloat16* __restrict__ outb, int N){
  __shared__ int   lds_s[4][64];
  __shared__ float lds_w[4][64*5];   // stride 5 -> conflict-free
  int wv = threadIdx.x >> 6, lane = threadIdx.x & 63;
  int n = blockIdx.x*4 + wv;
  if (n >= N) return;
  int g = lane >> 4, j = lane & 15, h = j >> 2;
  int rs = row_start[n], re = row_start[n+1];
  int deg = re - rs;

  float4 ern = er4[n];
  float acc[16];
  #pragma unroll
  for (int k = 0; k < 16; k++) acc[k] = 0.f;
  float m0 = -INFINITY, m1 = -INFINITY, m2 = -INFINITY, m3 = -INFINITY;
  float S0 = 0.f, S1 = 0.f, S2 = 0.f, S3 = 0.f;

  for (int base = rs; base < re; base += 64){
    int cnt = min(64, re - base);
    int s = 0;
    float x0 = -INFINITY, x1 = -INFINITY, x2 = -INFINITY, x3 = -INFINITY;
    if (lane < cnt){
      s = srcp[base + lane];
      float4 e4 = el4[s];
      x0 = e4.x + ern.x; x0 = x0 > 0.f ? x0 : 0.2f*x0;
      x1 = e4.y + ern.y; x1 = x1 > 0.f ? x1 : 0.2f*x1;
      x2 = e4.z + ern.z; x2 = x2 > 0.f ? x2 : 0.2f*x2;
      x3 = e4.w + ern.w; x3 = x3 > 0.f ? x3 : 0.2f*x3;
    }
    float c0 = x0, c1 = x1, c2 = x2, c3 = x3;
    #pragma unroll
    for (int o = 1; o < 64; o <<= 1){
      c0 = fmaxf(c0, __shfl_xor(c0, o)); c1 = fmaxf(c1, __shfl_xor(c1, o));
      c2 = fmaxf(c2, __shfl_xor(c2, o)); c3 = fmaxf(c3, __shfl_xor(c3, o));
    }
    float mn0 = fmaxf(m0, c0), mn1 = fmaxf(m1, c1), mn2 = fmaxf(m2, c2), mn3 = fmaxf(m3, c3);
    float sc0 = __expf(m0 - mn0), sc1 = __expf(m1 - mn1);
    float sc2 = __expf(m2 - mn2), sc3 = __expf(m3 - mn3);
    float w0 = (lane < cnt) ? __expf(x0 - mn0) : 0.f;
    float w1 = (lane < cnt) ? __expf(x1 - mn1) : 0.f;
    float w2 = (lane < cnt) ? __expf(x2 - mn2) : 0.f;
    float w3 = (lane < cnt) ? __expf(x3 - mn3) : 0.f;
    float t0 = w0, t1 = w1, t2 = w2, t3 = w3;
    #pragma unroll
    for (int o = 1; o < 64; o <<= 1){
      t0 += __shfl_xor(t0, o); t1 += __shfl_xor(t1, o);
      t2 += __shfl_xor(t2, o); t3 += __shfl_xor(t3, o);
    }
    S0 = S0*sc0 + t0; S1 = S1*sc1 + t1; S2 = S2*sc2 + t2; S3 = S3*sc3 + t3;
    m0 = mn0; m1 = mn1; m2 = mn2; m3 = mn3;
    float sch = (h == 0) ? sc0 : (h == 1) ? sc1 : (h == 2) ? sc2 : sc3;
    #pragma unroll
    for (int k = 0; k < 16; k++) acc[k] *= sch;
    lds_s[wv][lane] = s;
    lds_w[wv][lane*5+0] = w0; lds_w[wv][lane*5+1] = w1;
    lds_w[wv][lane*5+2] = w2; lds_w[wv][lane*5+3] = w3;
    int iters = (cnt + 3) >> 2;
    for (int i = 0; i < iters; i++){
      int e = i*4 + g;
      int sb  = lds_s[wv][e];
      float wb = lds_w[wv][e*5 + h];
      const uint4* rp = featq + (size_t)sb*32 + (j << 1);
      uint4 u0 = rp[0], u1 = rp[1];
      acc[0]  += bf_lo(u0.x)*wb; acc[1]  += bf_hi(u0.x)*wb;
      acc[2]  += bf_lo(u0.y)*wb; acc[3]  += bf_hi(u0.y)*wb;
      acc[4]  += bf_lo(u0.z)*wb; acc[5]  += bf_hi(u0.z)*wb;
      acc[6]  += bf_lo(u0.w)*wb; acc[7]  += bf_hi(u0.w)*wb;
      acc[8]  += bf_lo(u1.x)*wb; acc[9]  += bf_hi(u1.x)*wb;
      acc[10] += bf_lo(u1.y)*wb; acc[11] += bf_hi(u1.y)*wb;
      acc[12] += bf_lo(u1.z)*wb; acc[13] += bf_hi(u1.z)*wb;
      acc[14] += bf_lo(u1.w)*wb; acc[15] += bf_hi(u1.w)*wb;
    }
  }
  #pragma unroll
  for (int k = 0; k < 16; k++){
    acc[k] += __shfl_xor(acc[k], 16);
    acc[k] += __shfl_xor(acc[k], 32);
  }
  if (g == 0){
    float Sh = (h == 0) ? S0 : (h == 1) ? S1 : (h == 2) ? S2 : S3;
    float inv = (deg > 0) ? 1.f / Sh : 0.f;
    float4 b0 = *(const float4*)&bias[j*16 + 0];
    float4 b1 = *(const float4*)&bias[j*16 + 4];
    float4 b2 = *(const float4*)&bias[j*16 + 8];
    float4 b3 = *(const float4*)&bias[j*16 + 12];
    float v[16];
    v[0]=acc[0]*inv+b0.x;  v[1]=acc[1]*inv+b0.y;  v[2]=acc[2]*inv+b0.z;  v[3]=acc[3]*inv+b0.w;
    v[4]=acc[4]*inv+b1.x;  v[5]=acc[5]*inv+b1.y;  v[6]=acc[6]*inv+b1.z;  v[7]=acc[7]*inv+b1.w;
    v[8]=acc[8]*inv+b2.x;  v[9]=acc[9]*inv+b2.y;  v[10]=acc[10]*inv+b2.z; v[11]=acc[11]*inv+b2.w;
    v[12]=acc[12]*inv+b3.x; v[13]=acc[13]*inv+b3.y; v[14]=acc[14]*inv+b3.z; v[15]=acc[15]*inv+b3.w;
    #pragma unroll
    for (int k = 0; k < 16; k++) v[k] = fmaxf(v[k], 0.f);   // relu (layer 1)
    uint4 o0, o1;
    o0.x = packbf(v[0], v[1]);   o0.y = packbf(v[2], v[3]);
    o0.z = packbf(v[4], v[5]);   o0.w = packbf(v[6], v[7]);
    o1.x = packbf(v[8], v[9]);   o1.y = packbf(v[10], v[11]);
    o1.z = packbf(v[12], v[13]); o1.w = packbf(v[14], v[15]);
    uint4* op = (uint4*)outb + (size_t)n*32 + (j << 1);
    op[0] = o0; op[1] = o1;
  }
}

// ---------------- fused edge-softmax + aggregation, H=1 (layer 2) ----------------
// Wave per node. 4 groups x 16 lanes; lane j reads 8B (4 dims) of 128B row. fp32 out.
__global__ __launch_bounds__(256) void k_agg1(const uint2* __restrict__ featd, // [N][16] uint2
      const float* __restrict__ el, const float* __restrict__ er,
      const int* __restrict__ row_start, const int* __restrict__ srcp,
      const float* __restrict__ bias, float* __restrict__ out, int N){
  __shared__ int   lds_s[4][64];
  __shared__ float lds_w[4][64];
  int wv = threadIdx.x >> 6, lane = threadIdx.x & 63;
  int n = blockIdx.x*4 + wv;
  if (n >= N) return;
  int g = lane >> 4, j = lane & 15;
  int rs = row_start[n], re = row_start[n+1];
  int deg = re - rs;

  float ern = er[n];
  float acc[4] = {0.f, 0.f, 0.f, 0.f};
  float m = -INFINITY, S = 0.f;

  for (int base = rs; base < re; base += 64){
    int cnt = min(64, re - base);
    int s = 0;
    float x = -INFINITY;
    if (lane < cnt){
      s = srcp[base + lane];
      x = el[s] + ern;
      x = x > 0.f ? x : 0.2f*x;
    }
    float c = x;
    #pragma unroll
    for (int o = 1; o < 64; o <<= 1) c = fmaxf(c, __shfl_xor(c, o));
    float mn = fmaxf(m, c);
    float sc = __expf(m - mn);
    float w = (lane < cnt) ? __expf(x - mn) : 0.f;
    float t = w;
    #pragma unroll
    for (int o = 1; o < 64; o <<= 1) t += __shfl_xor(t, o);
    S = S*sc + t;
    m = mn;
    #pragma unroll
    for (int k = 0; k < 4; k++) acc[k] *= sc;
    lds_s[wv][lane] = s;
    lds_w[wv][lane] = w;
    int iters = (cnt + 3) >> 2;
    for (int i = 0; i < iters; i++){
      int e = i*4 + g;
      int sb  = lds_s[wv][e];
      float wb = lds_w[wv][e];
      uint2 u = featd[(size_t)sb*16 + j];
      acc[0] += bf_lo(u.x)*wb; acc[1] += bf_hi(u.x)*wb;
      acc[2] += bf_lo(u.y)*wb; acc[3] += bf_hi(u.y)*wb;
    }
  }
  #pragma unroll
  for (int k = 0; k < 4; k++){
    acc[k] += __shfl_xor(acc[k], 16);
    acc[k] += __shfl_xor(acc[k], 32);
  }
  if (g == 0){
    float inv = (deg > 0) ? 1.f / S : 0.f;
    float4 b = *(const float4*)&bias[j*4];
    float4 o;
    o.x = acc[0]*inv + b.x; o.y = acc[1]*inv + b.y;
    o.z = acc[2]*inv + b.z; o.w = acc[3]*inv + b.w;
    *(float4*)&out[(size_t)n*64 + j*4] = o;
  }
}

// ---------------- launch ----------------
extern "C" void kernel_launch(void* const* d_in, const int* in_sizes, int n_in,
                              void* d_out, int out_size, void* d_ws, size_t ws_size,
                              hipStream_t stream) {
  const float* emb = (const float*)d_in[0];
  const int*   src = (const int*)d_in[1];
  const int*   dst = (const int*)d_in[2];
  const float* W1  = (const float*)d_in[3];
  const float* al1 = (const float*)d_in[4];
  const float* ar1 = (const float*)d_in[5];
  const float* b1  = (const float*)d_in[6];
  const float* W2  = (const float*)d_in[7];
  const float* al2 = (const float*)d_in[8];
  const float* ar2 = (const float*)d_in[9];
  const float* b2  = (const float*)d_in[10];
  float* out = (float*)d_out;

  const int N = in_sizes[0] / 128;
  const int E = in_sizes[1];

  char* p = (char*)d_ws;
  auto alloc = [&](size_t bytes) -> void* {
    void* r = (void*)p; p += (bytes + 255) & ~(size_t)255; return r;
  };
  __hip_bfloat16* feat1b = (__hip_bfloat16*)alloc((size_t)N*256*2);
  __hip_bfloat16* h1b    = (__hip_bfloat16*)alloc((size_t)N*256*2);
  __hip_bfloat16* feat2b = (__hip_bfloat16*)alloc((size_t)N*64*2);
  float* el1             = (float*)alloc((size_t)N*4*4);
  float* er1             = (float*)alloc((size_t)N*4*4);
  float* el2             = (float*)alloc((size_t)N*4);
  float* er2             = (float*)alloc((size_t)N*4);
  int*   deg             = (int*)alloc((size_t)N*4);
  int*   row_start       = (int*)alloc((size_t)(N+1)*4);
  int*   cursor          = (int*)alloc((size_t)N*4);
  int*   blocksum        = (int*)alloc((size_t)DIV_UP(N,1024)*4);
  int*   srcp            = (int*)alloc((size_t)E*4);

  const int nb = DIV_UP(N, 1024);

  hipMemsetAsync(deg, 0, (size_t)N*4, stream);
  k_count_deg<<<DIV_UP(E,256), 256, 0, stream>>>(dst, deg, E);
  k_scan1<<<nb, 256, 0, stream>>>(deg, blocksum, N);
  k_scan2<<<1, 64, 0, stream>>>(blocksum, nb);
  k_scan3<<<nb, 256, 0, stream>>>(deg, blocksum, row_start, cursor, N);
  k_fill<<<DIV_UP(E,256), 256, 0, stream>>>(dst, src, cursor, srcp, E);

  // Layer 1: feat1b = bf16(emb @ W1), el1/er1 fused
  k_gemm<4,false><<<dim3(DIV_UP(N,64), 4), 256, 0, stream>>>(emb, W1, feat1b,
                                                             al1, ar1, el1, er1, N, 256, 128);
  k_agg4<<<DIV_UP(N,4), 256, 0, stream>>>((const uint4*)feat1b, (const float4*)el1,
                                          (const float4*)er1, row_start, srcp, b1, h1b, N);
  // Layer 2: feat2b = bf16(h1b @ W2), el2/er2 fused
  k_gemm<1,true><<<dim3(DIV_UP(N,64), 1), 256, 0, stream>>>(h1b, W2, feat2b,
                                                            al2, ar2, el2, er2, N, 64, 256);
  k_agg1<<<DIV_UP(N,4), 256, 0, stream>>>((const uint2*)feat2b, el2, er2,
                                          row_start, srcp, b2, out, N);
}

// Round 5
// 249.682 us; speedup vs baseline: 2.0971x; 1.1342x over previous
//
#include <hip/hip_runtime.h>
#include <hip/hip_bf16.h>
#include <math.h>

#define DIV_UP(a,b) (((a)+(b)-1)/(b))

typedef __attribute__((ext_vector_type(8))) short short8v;
typedef __attribute__((ext_vector_type(4))) float f32x4;

__device__ __forceinline__ float bf_lo(unsigned u){ union{unsigned x; float f;} v; v.x = u << 16; return v.f; }
__device__ __forceinline__ float bf_hi(unsigned u){ union{unsigned x; float f;} v; v.x = u & 0xffff0000u; return v.f; }
__device__ __forceinline__ unsigned short f2bf(float f){
  union{float f; unsigned u;} v; v.f = f;
  unsigned r = v.u + 0x7fff + ((v.u >> 16) & 1);   // round-nearest-even
  return (unsigned short)(r >> 16);
}
__device__ __forceinline__ unsigned packbf(float a, float b){
  return (unsigned)f2bf(a) | ((unsigned)f2bf(b) << 16);
}

// ---------------- CSR build ----------------
__global__ void k_count_deg(const int* __restrict__ dst, int* __restrict__ deg, int E){
  int i = blockIdx.x*blockDim.x + threadIdx.x;
  if (i < E) atomicAdd(&deg[dst[i]], 1);
}

__global__ __launch_bounds__(256) void k_scan1(const int* __restrict__ deg,
                                               int* __restrict__ blocksum, int N){
  int b = blockIdx.x;
  int base = b*1024 + threadIdx.x*4;
  int s = 0;
  if (base + 3 < N){
    int4 v = *(const int4*)&deg[base];
    s = v.x + v.y + v.z + v.w;
  } else {
    for (int i = 0; i < 4; i++){ int idx = base + i; if (idx < N) s += deg[idx]; }
  }
  #pragma unroll
  for (int o = 32; o; o >>= 1) s += __shfl_down(s, o);
  __shared__ int ws[4];
  int wid = threadIdx.x >> 6, lane = threadIdx.x & 63;
  if (lane == 0) ws[wid] = s;
  __syncthreads();
  if (threadIdx.x == 0) blocksum[b] = ws[0] + ws[1] + ws[2] + ws[3];
}

__global__ void k_scan2(int* __restrict__ blocksum, int nb){
  int lane = threadIdx.x;  // 64 threads
  int carry = 0;
  for (int base = 0; base < nb; base += 64){
    int idx = base + lane;
    int orig = (idx < nb) ? blocksum[idx] : 0;
    int v = orig;
    #pragma unroll
    for (int o = 1; o < 64; o <<= 1){ int t = __shfl_up(v, o); if (lane >= o) v += t; }
    if (idx < nb) blocksum[idx] = carry + v - orig;   // exclusive
    carry += __shfl(v, 63);
  }
}

__global__ __launch_bounds__(256) void k_scan3(const int* __restrict__ deg,
                                               const int* __restrict__ blockoff,
                                               int* __restrict__ row_start,
                                               int* __restrict__ cursor, int N){
  int b = blockIdx.x;
  int base = b*1024 + threadIdx.x*4;
  int v[4];
  #pragma unroll
  for (int i = 0; i < 4; i++){ int idx = base + i; v[i] = (idx < N) ? deg[idx] : 0; }
  int s = v[0] + v[1] + v[2] + v[3];
  int lane = threadIdx.x & 63, wid = threadIdx.x >> 6;
  int inc = s;
  #pragma unroll
  for (int o = 1; o < 64; o <<= 1){ int t = __shfl_up(inc, o); if (lane >= o) inc += t; }
  __shared__ int wsum[4];
  if (lane == 63) wsum[wid] = inc;
  __syncthreads();
  int woff = 0;
  #pragma unroll
  for (int i = 0; i < 4; i++) if (i < wid) woff += wsum[i];
  int run = blockoff[b] + woff + inc - s;
  #pragma unroll
  for (int i = 0; i < 4; i++){
    int idx = base + i;
    if (idx < N){ row_start[idx] = run; cursor[idx] = run; run += v[i]; }
  }
  if (base < N && base + 4 >= N) row_start[N] = run;
}

__global__ void k_fill(const int* __restrict__ dst, const int* __restrict__ src,
                       int* __restrict__ cursor, int* __restrict__ srcp, int E){
  int i = blockIdx.x*blockDim.x + threadIdx.x;
  if (i < E){ int p = atomicAdd(&cursor[dst[i]], 1); srcp[p] = src[i]; }
}

// ---------------- MFMA bf16 GEMM, 64x64 tile, full-K LDS, fused el/er ----------------
// C[M, H*64] tile at (blockIdx.x*64, by*64). A: fp32 (ABF=0) or bf16 (ABF=1).
// B fp32 [K][ldb]. Emits bf16 C + el/er per row for head by.
template<int K, int H, bool ABF>
__global__ __launch_bounds__(256) void k_gemm_mfma(const void* __restrict__ Av,
      const float* __restrict__ B, int ldb,
      unsigned short* __restrict__ Cbf,
      const float* __restrict__ al, const float* __restrict__ ar,
      float* __restrict__ el, float* __restrict__ er, int M){
  constexpr int KP = K + 8;   // pad 8 bf16 = 16B: keeps 16B align, breaks bank conflicts
  __shared__ alignas(16) __hip_bfloat16 At[64][KP];
  __shared__ alignas(16) __hip_bfloat16 Bt[64][KP];   // Bt[n][k] = B[k][n0+n]
  __shared__ float elp[2][64], erp[2][64];
  const int tid = threadIdx.x;
  const int lane = tid & 63, w = tid >> 6;
  const int mw = w >> 1, nw = w & 1;
  const int m0 = blockIdx.x * 64, by = blockIdx.y, n0 = by * 64;

  // stage A
  if constexpr (!ABF){
    const float* A = (const float*)Av;
    #pragma unroll
    for (int i = 0; i < K/16; i++){
      int q = tid + i*256;
      int row = q / (K/4), c4 = q % (K/4);
      float4 a = make_float4(0.f,0.f,0.f,0.f);
      if (m0 + row < M) a = *(const float4*)&A[(size_t)(m0+row)*K + c4*4];
      *(uint2*)&At[row][c4*4] = make_uint2(packbf(a.x,a.y), packbf(a.z,a.w));
    }
  } else {
    const __hip_bfloat16* A = (const __hip_bfloat16*)Av;
    #pragma unroll
    for (int i = 0; i < K/32; i++){
      int q = tid + i*256;
      int row = q / (K/8), c8 = q % (K/8);
      uint4 u = make_uint4(0,0,0,0);
      if (m0 + row < M) u = *(const uint4*)&A[(size_t)(m0+row)*K + c8*8];
      *(uint4*)&At[row][c8*8] = u;
    }
  }
  // stage B transposed
  #pragma unroll
  for (int i = 0; i < K/16; i++){
    int q = tid + i*256;
    int c = q & 63, k4 = q >> 6;
    float b0 = B[(size_t)(k4*4+0)*ldb + n0 + c];
    float b1 = B[(size_t)(k4*4+1)*ldb + n0 + c];
    float b2 = B[(size_t)(k4*4+2)*ldb + n0 + c];
    float b3 = B[(size_t)(k4*4+3)*ldb + n0 + c];
    *(uint2*)&Bt[c][k4*4] = make_uint2(packbf(b0,b1), packbf(b2,b3));
  }
  __syncthreads();

  f32x4 acc[2][2];
  #pragma unroll
  for (int i = 0; i < 2; i++)
    #pragma unroll
    for (int j = 0; j < 2; j++)
      #pragma unroll
      for (int r = 0; r < 4; r++) acc[i][j][r] = 0.f;

  const int rbase = mw*32, cbase = nw*32;
  const int fr = lane & 15, fg = lane >> 4;
  #pragma unroll
  for (int ks = 0; ks < K/32; ks++){
    short8v a0 = *(const short8v*)&At[rbase + fr     ][ks*32 + fg*8];
    short8v a1 = *(const short8v*)&At[rbase + 16 + fr][ks*32 + fg*8];
    short8v b0 = *(const short8v*)&Bt[cbase + fr     ][ks*32 + fg*8];
    short8v b1 = *(const short8v*)&Bt[cbase + 16 + fr][ks*32 + fg*8];
    acc[0][0] = __builtin_amdgcn_mfma_f32_16x16x32_bf16(a0, b0, acc[0][0], 0,0,0);
    acc[0][1] = __builtin_amdgcn_mfma_f32_16x16x32_bf16(a0, b1, acc[0][1], 0,0,0);
    acc[1][0] = __builtin_amdgcn_mfma_f32_16x16x32_bf16(a1, b0, acc[1][0], 0,0,0);
    acc[1][1] = __builtin_amdgcn_mfma_f32_16x16x32_bf16(a1, b1, acc[1][1], 0,0,0);
  }

  // el/er partials: row = rbase + mt*16 + fg*4 + r, col = cbase + nt*16 + fr
  float alv[2], arv[2];
  #pragma unroll
  for (int nt = 0; nt < 2; nt++){
    int col = cbase + nt*16 + fr;
    alv[nt] = al[by*64 + col];
    arv[nt] = ar[by*64 + col];
  }
  #pragma unroll
  for (int mt = 0; mt < 2; mt++){
    #pragma unroll
    for (int r = 0; r < 4; r++){
      float pl = acc[mt][0][r]*alv[0] + acc[mt][1][r]*alv[1];
      float pr = acc[mt][0][r]*arv[0] + acc[mt][1][r]*arv[1];
      #pragma unroll
      for (int o = 1; o < 16; o <<= 1){ pl += __shfl_xor(pl, o); pr += __shfl_xor(pr, o); }
      if (fr == 0){
        int rl = rbase + mt*16 + fg*4 + r;
        elp[nw][rl] = pl; erp[nw][rl] = pr;
      }
    }
  }
  // C store (bf16)
  const int NN = H*64;
  #pragma unroll
  for (int mt = 0; mt < 2; mt++){
    #pragma unroll
    for (int r = 0; r < 4; r++){
      int row = m0 + rbase + mt*16 + fg*4 + r;
      if (row < M){
        #pragma unroll
        for (int nt = 0; nt < 2; nt++)
          Cbf[(size_t)row*NN + n0 + cbase + nt*16 + fr] = f2bf(acc[mt][nt][r]);
      }
    }
  }
  __syncthreads();
  if (tid < 64){
    int row = m0 + tid;
    if (row < M){
      el[(size_t)row*H + by] = elp[0][tid] + elp[1][tid];
      er[(size_t)row*H + by] = erp[0][tid] + erp[1][tid];
    }
  }
}

// ---------------- fused edge-softmax + aggregation, H=4 (layer 1) ----------------
__global__ __launch_bounds__(256) void k_agg4(const char* __restrict__ featb, // bf16 [N][256]
      const float4* __restrict__ el4, const float4* __restrict__ er4,
      const int* __restrict__ row_start, const int* __restrict__ srcp,
      const float* __restrict__ bias, __hip_bfloat16* __restrict__ outb, int N){
  __shared__ int   lds_s[4][64];
  __shared__ float lds_w[4][64*5];
  int wv = threadIdx.x >> 6, lane = threadIdx.x & 63;
  int n = blockIdx.x*4 + wv;
  if (n >= N) return;
  int g = lane >> 4, j = lane & 15, h = j >> 2;
  int rs = row_start[n], re = row_start[n+1];
  int deg = re - rs;

  float4 ern = er4[n];
  float acc[16];
  #pragma unroll
  for (int k = 0; k < 16; k++) acc[k] = 0.f;
  float S0, S1, S2, S3;

  if (deg <= 64){
    // ---- fast path: single chunk, no online rescale ----
    int s = 0;
    float x0 = -INFINITY, x1 = -INFINITY, x2 = -INFINITY, x3 = -INFINITY;
    if (lane < deg){
      s = srcp[rs + lane];
      float4 e4 = el4[s];
      x0 = e4.x + ern.x; x0 = x0 > 0.f ? x0 : 0.2f*x0;
      x1 = e4.y + ern.y; x1 = x1 > 0.f ? x1 : 0.2f*x1;
      x2 = e4.z + ern.z; x2 = x2 > 0.f ? x2 : 0.2f*x2;
      x3 = e4.w + ern.w; x3 = x3 > 0.f ? x3 : 0.2f*x3;
    }
    float c0 = x0, c1 = x1, c2 = x2, c3 = x3;
    #pragma unroll
    for (int o = 1; o < 64; o <<= 1){
      c0 = fmaxf(c0, __shfl_xor(c0, o)); c1 = fmaxf(c1, __shfl_xor(c1, o));
      c2 = fmaxf(c2, __shfl_xor(c2, o)); c3 = fmaxf(c3, __shfl_xor(c3, o));
    }
    float w0 = (lane < deg) ? __expf(x0 - c0) : 0.f;
    float w1 = (lane < deg) ? __expf(x1 - c1) : 0.f;
    float w2 = (lane < deg) ? __expf(x2 - c2) : 0.f;
    float w3 = (lane < deg) ? __expf(x3 - c3) : 0.f;
    float t0 = w0, t1 = w1, t2 = w2, t3 = w3;
    #pragma unroll
    for (int o = 1; o < 64; o <<= 1){
      t0 += __shfl_xor(t0, o); t1 += __shfl_xor(t1, o);
      t2 += __shfl_xor(t2, o); t3 += __shfl_xor(t3, o);
    }
    S0 = t0; S1 = t1; S2 = t2; S3 = t3;
    lds_s[wv][lane] = s;
    lds_w[wv][lane*5+0] = w0; lds_w[wv][lane*5+1] = w1;
    lds_w[wv][lane*5+2] = w2; lds_w[wv][lane*5+3] = w3;
    int iters = (deg + 3) >> 2;
    unsigned jo = (unsigned)(j << 5);
    for (int i = 0; i < iters; i += 2){
      int e0 = i*4 + g;
      int sb0 = lds_s[wv][e0];
      float wb0 = lds_w[wv][e0*5 + h];
      unsigned off0 = (unsigned)sb0*512u + jo;
      uint4 u0 = *(const uint4*)(featb + off0);
      uint4 u1 = *(const uint4*)(featb + off0 + 16);
      bool has2 = (i + 1) < iters;
      int e1 = e0 + 4;
      int sb1 = has2 ? lds_s[wv][e1] : 0;
      float wb1 = has2 ? lds_w[wv][e1*5 + h] : 0.f;
      unsigned off1 = (unsigned)sb1*512u + jo;
      uint4 v0 = *(const uint4*)(featb + off1);
      uint4 v1 = *(const uint4*)(featb + off1 + 16);
      acc[0]  += bf_lo(u0.x)*wb0; acc[1]  += bf_hi(u0.x)*wb0;
      acc[2]  += bf_lo(u0.y)*wb0; acc[3]  += bf_hi(u0.y)*wb0;
      acc[4]  += bf_lo(u0.z)*wb0; acc[5]  += bf_hi(u0.z)*wb0;
      acc[6]  += bf_lo(u0.w)*wb0; acc[7]  += bf_hi(u0.w)*wb0;
      acc[8]  += bf_lo(u1.x)*wb0; acc[9]  += bf_hi(u1.x)*wb0;
      acc[10] += bf_lo(u1.y)*wb0; acc[11] += bf_hi(u1.y)*wb0;
      acc[12] += bf_lo(u1.z)*wb0; acc[13] += bf_hi(u1.z)*wb0;
      acc[14] += bf_lo(u1.w)*wb0; acc[15] += bf_hi(u1.w)*wb0;
      acc[0]  += bf_lo(v0.x)*wb1; acc[1]  += bf_hi(v0.x)*wb1;
      acc[2]  += bf_lo(v0.y)*wb1; acc[3]  += bf_hi(v0.y)*wb1;
      acc[4]  += bf_lo(v0.z)*wb1; acc[5]  += bf_hi(v0.z)*wb1;
      acc[6]  += bf_lo(v0.w)*wb1; acc[7]  += bf_hi(v0.w)*wb1;
      acc[8]  += bf_lo(v1.x)*wb1; acc[9]  += bf_hi(v1.x)*wb1;
      acc[10] += bf_lo(v1.y)*wb1; acc[11] += bf_hi(v1.y)*wb1;
      acc[12] += bf_lo(v1.z)*wb1; acc[13] += bf_hi(v1.z)*wb1;
      acc[14] += bf_lo(v1.w)*wb1; acc[15] += bf_hi(v1.w)*wb1;
    }
  } else {
    // ---- slow path: online softmax over 64-edge chunks ----
    float m0 = -INFINITY, m1 = -INFINITY, m2 = -INFINITY, m3 = -INFINITY;
    S0 = 0.f; S1 = 0.f; S2 = 0.f; S3 = 0.f;
    for (int base = rs; base < re; base += 64){
      int cnt = min(64, re - base);
      int s = 0;
      float x0 = -INFINITY, x1 = -INFINITY, x2 = -INFINITY, x3 = -INFINITY;
      if (lane < cnt){
        s = srcp[base + lane];
        float4 e4 = el4[s];
        x0 = e4.x + ern.x; x0 = x0 > 0.f ? x0 : 0.2f*x0;
        x1 = e4.y + ern.y; x1 = x1 > 0.f ? x1 : 0.2f*x1;
        x2 = e4.z + ern.z; x2 = x2 > 0.f ? x2 : 0.2f*x2;
        x3 = e4.w + ern.w; x3 = x3 > 0.f ? x3 : 0.2f*x3;
      }
      float c0 = x0, c1 = x1, c2 = x2, c3 = x3;
      #pragma unroll
      for (int o = 1; o < 64; o <<= 1){
        c0 = fmaxf(c0, __shfl_xor(c0, o)); c1 = fmaxf(c1, __shfl_xor(c1, o));
        c2 = fmaxf(c2, __shfl_xor(c2, o)); c3 = fmaxf(c3, __shfl_xor(c3, o));
      }
      float mn0 = fmaxf(m0, c0), mn1 = fmaxf(m1, c1), mn2 = fmaxf(m2, c2), mn3 = fmaxf(m3, c3);
      float sc0 = __expf(m0 - mn0), sc1 = __expf(m1 - mn1);
      float sc2 = __expf(m2 - mn2), sc3 = __expf(m3 - mn3);
      float w0 = (lane < cnt) ? __expf(x0 - mn0) : 0.f;
      float w1 = (lane < cnt) ? __expf(x1 - mn1) : 0.f;
      float w2 = (lane < cnt) ? __expf(x2 - mn2) : 0.f;
      float w3 = (lane < cnt) ? __expf(x3 - mn3) : 0.f;
      float t0 = w0, t1 = w1, t2 = w2, t3 = w3;
      #pragma unroll
      for (int o = 1; o < 64; o <<= 1){
        t0 += __shfl_xor(t0, o); t1 += __shfl_xor(t1, o);
        t2 += __shfl_xor(t2, o); t3 += __shfl_xor(t3, o);
      }
      S0 = S0*sc0 + t0; S1 = S1*sc1 + t1; S2 = S2*sc2 + t2; S3 = S3*sc3 + t3;
      m0 = mn0; m1 = mn1; m2 = mn2; m3 = mn3;
      float sch = (h == 0) ? sc0 : (h == 1) ? sc1 : (h == 2) ? sc2 : sc3;
      #pragma unroll
      for (int k = 0; k < 16; k++) acc[k] *= sch;
      lds_s[wv][lane] = s;
      lds_w[wv][lane*5+0] = w0; lds_w[wv][lane*5+1] = w1;
      lds_w[wv][lane*5+2] = w2; lds_w[wv][lane*5+3] = w3;
      int iters = (cnt + 3) >> 2;
      for (int i = 0; i < iters; i++){
        int e = i*4 + g;
        int sb  = lds_s[wv][e];
        float wb = lds_w[wv][e*5 + h];
        unsigned off = (unsigned)sb*512u + (unsigned)(j << 5);
        uint4 u0 = *(const uint4*)(featb + off);
        uint4 u1 = *(const uint4*)(featb + off + 16);
        acc[0]  += bf_lo(u0.x)*wb; acc[1]  += bf_hi(u0.x)*wb;
        acc[2]  += bf_lo(u0.y)*wb; acc[3]  += bf_hi(u0.y)*wb;
        acc[4]  += bf_lo(u0.z)*wb; acc[5]  += bf_hi(u0.z)*wb;
        acc[6]  += bf_lo(u0.w)*wb; acc[7]  += bf_hi(u0.w)*wb;
        acc[8]  += bf_lo(u1.x)*wb; acc[9]  += bf_hi(u1.x)*wb;
        acc[10] += bf_lo(u1.y)*wb; acc[11] += bf_hi(u1.y)*wb;
        acc[12] += bf_lo(u1.z)*wb; acc[13] += bf_hi(u1.z)*wb;
        acc[14] += bf_lo(u1.w)*wb; acc[15] += bf_hi(u1.w)*wb;
      }
    }
  }

  #pragma unroll
  for (int k = 0; k < 16; k++){
    acc[k] += __shfl_xor(acc[k], 16);
    acc[k] += __shfl_xor(acc[k], 32);
  }
  if (g == 0){
    float Sh = (h == 0) ? S0 : (h == 1) ? S1 : (h == 2) ? S2 : S3;
    float inv = (deg > 0) ? 1.f / Sh : 0.f;
    float4 b0 = *(const float4*)&bias[j*16 + 0];
    float4 b1 = *(const float4*)&bias[j*16 + 4];
    float4 b2 = *(const float4*)&bias[j*16 + 8];
    float4 b3 = *(const float4*)&bias[j*16 + 12];
    float v[16];
    v[0]=acc[0]*inv+b0.x;  v[1]=acc[1]*inv+b0.y;  v[2]=acc[2]*inv+b0.z;  v[3]=acc[3]*inv+b0.w;
    v[4]=acc[4]*inv+b1.x;  v[5]=acc[5]*inv+b1.y;  v[6]=acc[6]*inv+b1.z;  v[7]=acc[7]*inv+b1.w;
    v[8]=acc[8]*inv+b2.x;  v[9]=acc[9]*inv+b2.y;  v[10]=acc[10]*inv+b2.z; v[11]=acc[11]*inv+b2.w;
    v[12]=acc[12]*inv+b3.x; v[13]=acc[13]*inv+b3.y; v[14]=acc[14]*inv+b3.z; v[15]=acc[15]*inv+b3.w;
    #pragma unroll
    for (int k = 0; k < 16; k++) v[k] = fmaxf(v[k], 0.f);   // relu (layer 1)
    uint4 o0, o1;
    o0.x = packbf(v[0], v[1]);   o0.y = packbf(v[2], v[3]);
    o0.z = packbf(v[4], v[5]);   o0.w = packbf(v[6], v[7]);
    o1.x = packbf(v[8], v[9]);   o1.y = packbf(v[10], v[11]);
    o1.z = packbf(v[12], v[13]); o1.w = packbf(v[14], v[15]);
    uint4* op = (uint4*)outb + (size_t)n*32 + (j << 1);
    op[0] = o0; op[1] = o1;
  }
}

// ---------------- fused edge-softmax + aggregation, H=1 (layer 2) ----------------
__global__ __launch_bounds__(256) void k_agg1(const char* __restrict__ featb, // bf16 [N][64]
      const float* __restrict__ el, const float* __restrict__ er,
      const int* __restrict__ row_start, const int* __restrict__ srcp,
      const float* __restrict__ bias, float* __restrict__ out, int N){
  __shared__ int   lds_s[4][64];
  __shared__ float lds_w[4][64];
  int wv = threadIdx.x >> 6, lane = threadIdx.x & 63;
  int n = blockIdx.x*4 + wv;
  if (n >= N) return;
  int g = lane >> 4, j = lane & 15;
  int rs = row_start[n], re = row_start[n+1];
  int deg = re - rs;

  float ern = er[n];
  float acc[4] = {0.f, 0.f, 0.f, 0.f};
  float S;

  if (deg <= 64){
    int s = 0;
    float x = -INFINITY;
    if (lane < deg){
      s = srcp[rs + lane];
      x = el[s] + ern;
      x = x > 0.f ? x : 0.2f*x;
    }
    float c = x;
    #pragma unroll
    for (int o = 1; o < 64; o <<= 1) c = fmaxf(c, __shfl_xor(c, o));
    float w = (lane < deg) ? __expf(x - c) : 0.f;
    float t = w;
    #pragma unroll
    for (int o = 1; o < 64; o <<= 1) t += __shfl_xor(t, o);
    S = t;
    lds_s[wv][lane] = s;
    lds_w[wv][lane] = w;
    int iters = (deg + 3) >> 2;
    unsigned jo = (unsigned)(j << 3);
    for (int i = 0; i < iters; i += 2){
      int e0 = i*4 + g;
      int sb0 = lds_s[wv][e0];
      float wb0 = lds_w[wv][e0];
      uint2 u = *(const uint2*)(featb + (unsigned)sb0*128u + jo);
      bool has2 = (i + 1) < iters;
      int e1 = e0 + 4;
      int sb1 = has2 ? lds_s[wv][e1] : 0;
      float wb1 = has2 ? lds_w[wv][e1] : 0.f;
      uint2 v2 = *(const uint2*)(featb + (unsigned)sb1*128u + jo);
      acc[0] += bf_lo(u.x)*wb0; acc[1] += bf_hi(u.x)*wb0;
      acc[2] += bf_lo(u.y)*wb0; acc[3] += bf_hi(u.y)*wb0;
      acc[0] += bf_lo(v2.x)*wb1; acc[1] += bf_hi(v2.x)*wb1;
      acc[2] += bf_lo(v2.y)*wb1; acc[3] += bf_hi(v2.y)*wb1;
    }
  } else {
    float m = -INFINITY;
    S = 0.f;
    for (int base = rs; base < re; base += 64){
      int cnt = min(64, re - base);
      int s = 0;
      float x = -INFINITY;
      if (lane < cnt){
        s = srcp[base + lane];
        x = el[s] + ern;
        x = x > 0.f ? x : 0.2f*x;
      }
      float c = x;
      #pragma unroll
      for (int o = 1; o < 64; o <<= 1) c = fmaxf(c, __shfl_xor(c, o));
      float mn = fmaxf(m, c);
      float sc = __expf(m - mn);
      float w = (lane < cnt) ? __expf(x - mn) : 0.f;
      float t = w;
      #pragma unroll
      for (int o = 1; o < 64; o <<= 1) t += __shfl_xor(t, o);
      S = S*sc + t;
      m = mn;
      #pragma unroll
      for (int k = 0; k < 4; k++) acc[k] *= sc;
      lds_s[wv][lane] = s;
      lds_w[wv][lane] = w;
      int iters = (cnt + 3) >> 2;
      for (int i = 0; i < iters; i++){
        int e = i*4 + g;
        int sb  = lds_s[wv][e];
        float wb = lds_w[wv][e];
        uint2 u = *(const uint2*)(featb + (unsigned)sb*128u + (unsigned)(j << 3));
        acc[0] += bf_lo(u.x)*wb; acc[1] += bf_hi(u.x)*wb;
        acc[2] += bf_lo(u.y)*wb; acc[3] += bf_hi(u.y)*wb;
      }
    }
  }

  #pragma unroll
  for (int k = 0; k < 4; k++){
    acc[k] += __shfl_xor(acc[k], 16);
    acc[k] += __shfl_xor(acc[k], 32);
  }
  if (g == 0){
    float inv = (deg > 0) ? 1.f / S : 0.f;
    float4 b = *(const float4*)&bias[j*4];
    float4 o;
    o.x = acc[0]*inv + b.x; o.y = acc[1]*inv + b.y;
    o.z = acc[2]*inv + b.z; o.w = acc[3]*inv + b.w;
    *(float4*)&out[(size_t)n*64 + j*4] = o;
  }
}

// ---------------- launch ----------------
extern "C" void kernel_launch(void* const* d_in, const int* in_sizes, int n_in,
                              void* d_out, int out_size, void* d_ws, size_t ws_size,
                              hipStream_t stream) {
  const float* emb = (const float*)d_in[0];
  const int*   src = (const int*)d_in[1];
  const int*   dst = (const int*)d_in[2];
  const float* W1  = (const float*)d_in[3];
  const float* al1 = (const float*)d_in[4];
  const float* ar1 = (const float*)d_in[5];
  const float* b1  = (const float*)d_in[6];
  const float* W2  = (const float*)d_in[7];
  const float* al2 = (const float*)d_in[8];
  const float* ar2 = (const float*)d_in[9];
  const float* b2  = (const float*)d_in[10];
  float* out = (float*)d_out;

  const int N = in_sizes[0] / 128;
  const int E = in_sizes[1];

  char* p = (char*)d_ws;
  auto alloc = [&](size_t bytes) -> void* {
    void* r = (void*)p; p += (bytes + 255) & ~(size_t)255; return r;
  };
  __hip_bfloat16* feat1b = (__hip_bfloat16*)alloc((size_t)N*256*2);
  __hip_bfloat16* h1b    = (__hip_bfloat16*)alloc((size_t)N*256*2);
  __hip_bfloat16* feat2b = (__hip_bfloat16*)alloc((size_t)N*64*2);
  float* el1             = (float*)alloc((size_t)N*4*4);
  float* er1             = (float*)alloc((size_t)N*4*4);
  float* el2             = (float*)alloc((size_t)N*4);
  float* er2             = (float*)alloc((size_t)N*4);
  int*   deg             = (int*)alloc((size_t)N*4);
  int*   row_start       = (int*)alloc((size_t)(N+1)*4);
  int*   cursor          = (int*)alloc((size_t)N*4);
  int*   blocksum        = (int*)alloc((size_t)DIV_UP(N,1024)*4);
  int*   srcp            = (int*)alloc((size_t)E*4);

  const int nb = DIV_UP(N, 1024);

  hipMemsetAsync(deg, 0, (size_t)N*4, stream);
  k_count_deg<<<DIV_UP(E,256), 256, 0, stream>>>(dst, deg, E);
  k_scan1<<<nb, 256, 0, stream>>>(deg, blocksum, N);
  k_scan2<<<1, 64, 0, stream>>>(blocksum, nb);
  k_scan3<<<nb, 256, 0, stream>>>(deg, blocksum, row_start, cursor, N);
  k_fill<<<DIV_UP(E,256), 256, 0, stream>>>(dst, src, cursor, srcp, E);

  // Layer 1: feat1b = bf16(emb @ W1), el1/er1 fused.  K=128, H=4
  k_gemm_mfma<128,4,false><<<dim3(DIV_UP(N,64), 4), 256, 0, stream>>>(
      emb, W1, 256, (unsigned short*)feat1b, al1, ar1, el1, er1, N);
  k_agg4<<<DIV_UP(N,4), 256, 0, stream>>>((const char*)feat1b, (const float4*)el1,
                                          (const float4*)er1, row_start, srcp, b1, h1b, N);
  // Layer 2: feat2b = bf16(h1b @ W2), el2/er2 fused.  K=256, H=1
  k_gemm_mfma<256,1,true><<<dim3(DIV_UP(N,64), 1), 256, 0, stream>>>(
      h1b, W2, 64, (unsigned short*)feat2b, al2, ar2, el2, er2, N);
  k_agg1<<<DIV_UP(N,4), 256, 0, stream>>>((const char*)feat2b, el2, er2,
                                          row_start, srcp, b2, out, N);
}

// Round 6
// 247.506 us; speedup vs baseline: 2.1155x; 1.0088x over previous
//
#include <hip/hip_runtime.h>
#include <hip/hip_bf16.h>
#include <math.h>

#define DIV_UP(a,b) (((a)+(b)-1)/(b))

typedef __attribute__((ext_vector_type(8))) short short8v;
typedef __attribute__((ext_vector_type(4))) float f32x4;

__device__ __forceinline__ float bf_lo(unsigned u){ union{unsigned x; float f;} v; v.x = u << 16; return v.f; }
__device__ __forceinline__ float bf_hi(unsigned u){ union{unsigned x; float f;} v; v.x = u & 0xffff0000u; return v.f; }
__device__ __forceinline__ unsigned short f2bf(float f){
  union{float f; unsigned u;} v; v.f = f;
  unsigned r = v.u + 0x7fff + ((v.u >> 16) & 1);   // round-nearest-even
  return (unsigned short)(r >> 16);
}
__device__ __forceinline__ unsigned packbf(float a, float b){
  return (unsigned)f2bf(a) | ((unsigned)f2bf(b) << 16);
}
__device__ __forceinline__ float lrelu(float x){ return x > 0.f ? x : 0.2f*x; }

// ---------------- CSR build ----------------
__global__ void k_count_deg(const int* __restrict__ dst, int* __restrict__ deg, int E){
  int i = blockIdx.x*blockDim.x + threadIdx.x;
  if (i < E) atomicAdd(&deg[dst[i]], 1);
}

__global__ __launch_bounds__(256) void k_scan1(const int* __restrict__ deg,
                                               int* __restrict__ blocksum, int N){
  int b = blockIdx.x;
  int base = b*1024 + threadIdx.x*4;
  int s = 0;
  if (base + 3 < N){
    int4 v = *(const int4*)&deg[base];
    s = v.x + v.y + v.z + v.w;
  } else {
    for (int i = 0; i < 4; i++){ int idx = base + i; if (idx < N) s += deg[idx]; }
  }
  #pragma unroll
  for (int o = 32; o; o >>= 1) s += __shfl_down(s, o);
  __shared__ int ws[4];
  int wid = threadIdx.x >> 6, lane = threadIdx.x & 63;
  if (lane == 0) ws[wid] = s;
  __syncthreads();
  if (threadIdx.x == 0) blocksum[b] = ws[0] + ws[1] + ws[2] + ws[3];
}

__global__ void k_scan2(int* __restrict__ blocksum, int nb){
  int lane = threadIdx.x;  // 64 threads
  int carry = 0;
  for (int base = 0; base < nb; base += 64){
    int idx = base + lane;
    int orig = (idx < nb) ? blocksum[idx] : 0;
    int v = orig;
    #pragma unroll
    for (int o = 1; o < 64; o <<= 1){ int t = __shfl_up(v, o); if (lane >= o) v += t; }
    if (idx < nb) blocksum[idx] = carry + v - orig;   // exclusive
    carry += __shfl(v, 63);
  }
}

__global__ __launch_bounds__(256) void k_scan3(const int* __restrict__ deg,
                                               const int* __restrict__ blockoff,
                                               int* __restrict__ row_start,
                                               int* __restrict__ cursor, int N){
  int b = blockIdx.x;
  int base = b*1024 + threadIdx.x*4;
  int v[4];
  #pragma unroll
  for (int i = 0; i < 4; i++){ int idx = base + i; v[i] = (idx < N) ? deg[idx] : 0; }
  int s = v[0] + v[1] + v[2] + v[3];
  int lane = threadIdx.x & 63, wid = threadIdx.x >> 6;
  int inc = s;
  #pragma unroll
  for (int o = 1; o < 64; o <<= 1){ int t = __shfl_up(inc, o); if (lane >= o) inc += t; }
  __shared__ int wsum[4];
  if (lane == 63) wsum[wid] = inc;
  __syncthreads();
  int woff = 0;
  #pragma unroll
  for (int i = 0; i < 4; i++) if (i < wid) woff += wsum[i];
  int run = blockoff[b] + woff + inc - s;
  #pragma unroll
  for (int i = 0; i < 4; i++){
    int idx = base + i;
    if (idx < N){ row_start[idx] = run; cursor[idx] = run; run += v[i]; }
  }
  if (base < N && base + 4 >= N) row_start[N] = run;
}

// fill + layer-1 edge weights fused: one pass over original edges.
// exp() without max-shift: scores bounded (|x| << 88), softmax is shift-invariant.
__global__ void k_fillw4(const int* __restrict__ dst, const int* __restrict__ src,
                         int* __restrict__ cursor, int* __restrict__ srcp,
                         int* __restrict__ dstp,
                         const float4* __restrict__ el4, const float4* __restrict__ er4,
                         float4* __restrict__ w4, int E){
  int i = blockIdx.x*blockDim.x + threadIdx.x;
  if (i < E){
    int d = dst[i], s = src[i];
    int p = atomicAdd(&cursor[d], 1);
    srcp[p] = s; dstp[p] = d;
    float4 l = el4[s], r = er4[d];
    float4 w;
    w.x = __expf(lrelu(l.x + r.x));
    w.y = __expf(lrelu(l.y + r.y));
    w.z = __expf(lrelu(l.z + r.z));
    w.w = __expf(lrelu(l.w + r.w));
    w4[p] = w;
  }
}

// layer-2 edge weights: sequential pass over CSR slots
__global__ void k_edgew1(const int* __restrict__ srcp, const int* __restrict__ dstp,
                         const float* __restrict__ el, const float* __restrict__ er,
                         float* __restrict__ w1, int E){
  int i = blockIdx.x*blockDim.x + threadIdx.x;
  if (i < E) w1[i] = __expf(lrelu(el[srcp[i]] + er[dstp[i]]));
}

// ---------------- MFMA bf16 GEMM, 64x64 tile, full-K LDS, fused el/er ----------------
template<int K, int H, bool ABF>
__global__ __launch_bounds__(256) void k_gemm_mfma(const void* __restrict__ Av,
      const float* __restrict__ B, int ldb,
      unsigned short* __restrict__ Cbf,
      const float* __restrict__ al, const float* __restrict__ ar,
      float* __restrict__ el, float* __restrict__ er, int M){
  constexpr int KP = K + 8;
  __shared__ alignas(16) __hip_bfloat16 At[64][KP];
  __shared__ alignas(16) __hip_bfloat16 Bt[64][KP];
  __shared__ float elp[2][64], erp[2][64];
  const int tid = threadIdx.x;
  const int lane = tid & 63, w = tid >> 6;
  const int mw = w >> 1, nw = w & 1;
  const int m0 = blockIdx.x * 64, by = blockIdx.y, n0 = by * 64;

  if constexpr (!ABF){
    const float* A = (const float*)Av;
    #pragma unroll
    for (int i = 0; i < K/16; i++){
      int q = tid + i*256;
      int row = q / (K/4), c4 = q % (K/4);
      float4 a = make_float4(0.f,0.f,0.f,0.f);
      if (m0 + row < M) a = *(const float4*)&A[(size_t)(m0+row)*K + c4*4];
      *(uint2*)&At[row][c4*4] = make_uint2(packbf(a.x,a.y), packbf(a.z,a.w));
    }
  } else {
    const __hip_bfloat16* A = (const __hip_bfloat16*)Av;
    #pragma unroll
    for (int i = 0; i < K/32; i++){
      int q = tid + i*256;
      int row = q / (K/8), c8 = q % (K/8);
      uint4 u = make_uint4(0,0,0,0);
      if (m0 + row < M) u = *(const uint4*)&A[(size_t)(m0+row)*K + c8*8];
      *(uint4*)&At[row][c8*8] = u;
    }
  }
  #pragma unroll
  for (int i = 0; i < K/16; i++){
    int q = tid + i*256;
    int c = q & 63, k4 = q >> 6;
    float b0 = B[(size_t)(k4*4+0)*ldb + n0 + c];
    float b1 = B[(size_t)(k4*4+1)*ldb + n0 + c];
    float b2 = B[(size_t)(k4*4+2)*ldb + n0 + c];
    float b3 = B[(size_t)(k4*4+3)*ldb + n0 + c];
    *(uint2*)&Bt[c][k4*4] = make_uint2(packbf(b0,b1), packbf(b2,b3));
  }
  __syncthreads();

  f32x4 acc[2][2];
  #pragma unroll
  for (int i = 0; i < 2; i++)
    #pragma unroll
    for (int j = 0; j < 2; j++)
      #pragma unroll
      for (int r = 0; r < 4; r++) acc[i][j][r] = 0.f;

  const int rbase = mw*32, cbase = nw*32;
  const int fr = lane & 15, fg = lane >> 4;
  #pragma unroll
  for (int ks = 0; ks < K/32; ks++){
    short8v a0 = *(const short8v*)&At[rbase + fr     ][ks*32 + fg*8];
    short8v a1 = *(const short8v*)&At[rbase + 16 + fr][ks*32 + fg*8];
    short8v b0 = *(const short8v*)&Bt[cbase + fr     ][ks*32 + fg*8];
    short8v b1 = *(const short8v*)&Bt[cbase + 16 + fr][ks*32 + fg*8];
    acc[0][0] = __builtin_amdgcn_mfma_f32_16x16x32_bf16(a0, b0, acc[0][0], 0,0,0);
    acc[0][1] = __builtin_amdgcn_mfma_f32_16x16x32_bf16(a0, b1, acc[0][1], 0,0,0);
    acc[1][0] = __builtin_amdgcn_mfma_f32_16x16x32_bf16(a1, b0, acc[1][0], 0,0,0);
    acc[1][1] = __builtin_amdgcn_mfma_f32_16x16x32_bf16(a1, b1, acc[1][1], 0,0,0);
  }

  float alv[2], arv[2];
  #pragma unroll
  for (int nt = 0; nt < 2; nt++){
    int col = cbase + nt*16 + fr;
    alv[nt] = al[by*64 + col];
    arv[nt] = ar[by*64 + col];
  }
  #pragma unroll
  for (int mt = 0; mt < 2; mt++){
    #pragma unroll
    for (int r = 0; r < 4; r++){
      float pl = acc[mt][0][r]*alv[0] + acc[mt][1][r]*alv[1];
      float pr = acc[mt][0][r]*arv[0] + acc[mt][1][r]*arv[1];
      #pragma unroll
      for (int o = 1; o < 16; o <<= 1){ pl += __shfl_xor(pl, o); pr += __shfl_xor(pr, o); }
      if (fr == 0){
        int rl = rbase + mt*16 + fg*4 + r;
        elp[nw][rl] = pl; erp[nw][rl] = pr;
      }
    }
  }
  const int NN = H*64;
  #pragma unroll
  for (int mt = 0; mt < 2; mt++){
    #pragma unroll
    for (int r = 0; r < 4; r++){
      int row = m0 + rbase + mt*16 + fg*4 + r;
      if (row < M){
        #pragma unroll
        for (int nt = 0; nt < 2; nt++)
          Cbf[(size_t)row*NN + n0 + cbase + nt*16 + fr] = f2bf(acc[mt][nt][r]);
      }
    }
  }
  __syncthreads();
  if (tid < 64){
    int row = m0 + tid;
    if (row < M){
      el[(size_t)row*H + by] = elp[0][tid] + elp[1][tid];
      er[(size_t)row*H + by] = erp[0][tid] + erp[1][tid];
    }
  }
}

// ---------------- pure gather-aggregate, H=4 (layer 1) ----------------
// Wave per node. 4 groups x 16 lanes; group g takes edge i*4+g; lane j reads
// 32B (16 dims, one head) of the 512B bf16 row. 4-edge unroll -> 8 loads in flight.
__global__ __launch_bounds__(256) void k_gath4(const char* __restrict__ featb,
      const float* __restrict__ w4, const int* __restrict__ row_start,
      const int* __restrict__ srcp, const float* __restrict__ bias,
      __hip_bfloat16* __restrict__ outb, int N){
  int wv = threadIdx.x >> 6, lane = threadIdx.x & 63;
  int n = blockIdx.x*4 + wv;
  if (n >= N) return;
  int g = lane >> 4, j = lane & 15, h = j >> 2;
  int rs = row_start[n], deg = row_start[n+1] - rs;

  float acc[16];
  #pragma unroll
  for (int k = 0; k < 16; k++) acc[k] = 0.f;
  float Sacc = 0.f;
  unsigned jo = (unsigned)(j << 5);

  int iters = (deg + 3) >> 2;
  for (int i = 0; i < iters; i += 4){
    float wb[4]; uint4 u0[4], u1[4];
    #pragma unroll
    for (int k = 0; k < 4; k++){
      int e = (i + k)*4 + g;
      wb[k] = 0.f;
      u0[k] = make_uint4(0,0,0,0); u1[k] = make_uint4(0,0,0,0);
      if (e < deg){
        int sb = srcp[rs + e];
        wb[k] = w4[(size_t)(rs + e)*4 + h];
        const char* p = featb + (size_t)sb*512u + jo;
        u0[k] = *(const uint4*)p;
        u1[k] = *(const uint4*)(p + 16);
      }
    }
    #pragma unroll
    for (int k = 0; k < 4; k++){
      float wk = wb[k];
      Sacc += wk;
      acc[0]  += bf_lo(u0[k].x)*wk; acc[1]  += bf_hi(u0[k].x)*wk;
      acc[2]  += bf_lo(u0[k].y)*wk; acc[3]  += bf_hi(u0[k].y)*wk;
      acc[4]  += bf_lo(u0[k].z)*wk; acc[5]  += bf_hi(u0[k].z)*wk;
      acc[6]  += bf_lo(u0[k].w)*wk; acc[7]  += bf_hi(u0[k].w)*wk;
      acc[8]  += bf_lo(u1[k].x)*wk; acc[9]  += bf_hi(u1[k].x)*wk;
      acc[10] += bf_lo(u1[k].y)*wk; acc[11] += bf_hi(u1[k].y)*wk;
      acc[12] += bf_lo(u1[k].z)*wk; acc[13] += bf_hi(u1[k].z)*wk;
      acc[14] += bf_lo(u1[k].w)*wk; acc[15] += bf_hi(u1[k].w)*wk;
    }
  }
  #pragma unroll
  for (int k = 0; k < 16; k++){
    acc[k] += __shfl_xor(acc[k], 16);
    acc[k] += __shfl_xor(acc[k], 32);
  }
  Sacc += __shfl_xor(Sacc, 16);
  Sacc += __shfl_xor(Sacc, 32);
  if (g == 0){
    float inv = (deg > 0 && Sacc > 0.f) ? 1.f / Sacc : 0.f;
    float4 b0 = *(const float4*)&bias[j*16 + 0];
    float4 b1 = *(const float4*)&bias[j*16 + 4];
    float4 b2 = *(const float4*)&bias[j*16 + 8];
    float4 b3 = *(const float4*)&bias[j*16 + 12];
    float v[16];
    v[0]=acc[0]*inv+b0.x;  v[1]=acc[1]*inv+b0.y;  v[2]=acc[2]*inv+b0.z;  v[3]=acc[3]*inv+b0.w;
    v[4]=acc[4]*inv+b1.x;  v[5]=acc[5]*inv+b1.y;  v[6]=acc[6]*inv+b1.z;  v[7]=acc[7]*inv+b1.w;
    v[8]=acc[8]*inv+b2.x;  v[9]=acc[9]*inv+b2.y;  v[10]=acc[10]*inv+b2.z; v[11]=acc[11]*inv+b2.w;
    v[12]=acc[12]*inv+b3.x; v[13]=acc[13]*inv+b3.y; v[14]=acc[14]*inv+b3.z; v[15]=acc[15]*inv+b3.w;
    #pragma unroll
    for (int k = 0; k < 16; k++) v[k] = fmaxf(v[k], 0.f);   // relu (layer 1)
    uint4 o0, o1;
    o0.x = packbf(v[0], v[1]);   o0.y = packbf(v[2], v[3]);
    o0.z = packbf(v[4], v[5]);   o0.w = packbf(v[6], v[7]);
    o1.x = packbf(v[8], v[9]);   o1.y = packbf(v[10], v[11]);
    o1.z = packbf(v[12], v[13]); o1.w = packbf(v[14], v[15]);
    uint4* op = (uint4*)outb + (size_t)n*32 + (j << 1);
    op[0] = o0; op[1] = o1;
  }
}

// ---------------- pure gather-aggregate, H=1 (layer 2), fp32 out ----------------
__global__ __launch_bounds__(256) void k_gath1(const char* __restrict__ featb,
      const float* __restrict__ w1, const int* __restrict__ row_start,
      const int* __restrict__ srcp, const float* __restrict__ bias,
      float* __restrict__ out, int N){
  int wv = threadIdx.x >> 6, lane = threadIdx.x & 63;
  int n = blockIdx.x*4 + wv;
  if (n >= N) return;
  int g = lane >> 4, j = lane & 15;
  int rs = row_start[n], deg = row_start[n+1] - rs;

  float acc[4] = {0.f, 0.f, 0.f, 0.f};
  float Sacc = 0.f;
  unsigned jo = (unsigned)(j << 3);

  int iters = (deg + 3) >> 2;
  for (int i = 0; i < iters; i += 4){
    float wb[4]; uint2 u[4];
    #pragma unroll
    for (int k = 0; k < 4; k++){
      int e = (i + k)*4 + g;
      wb[k] = 0.f;
      u[k] = make_uint2(0,0);
      if (e < deg){
        int sb = srcp[rs + e];
        wb[k] = w1[rs + e];
        u[k] = *(const uint2*)(featb + (size_t)sb*128u + jo);
      }
    }
    #pragma unroll
    for (int k = 0; k < 4; k++){
      float wk = wb[k];
      Sacc += wk;
      acc[0] += bf_lo(u[k].x)*wk; acc[1] += bf_hi(u[k].x)*wk;
      acc[2] += bf_lo(u[k].y)*wk; acc[3] += bf_hi(u[k].y)*wk;
    }
  }
  #pragma unroll
  for (int k = 0; k < 4; k++){
    acc[k] += __shfl_xor(acc[k], 16);
    acc[k] += __shfl_xor(acc[k], 32);
  }
  Sacc += __shfl_xor(Sacc, 16);
  Sacc += __shfl_xor(Sacc, 32);
  if (g == 0){
    float inv = (deg > 0 && Sacc > 0.f) ? 1.f / Sacc : 0.f;
    float4 b = *(const float4*)&bias[j*4];
    float4 o;
    o.x = acc[0]*inv + b.x; o.y = acc[1]*inv + b.y;
    o.z = acc[2]*inv + b.z; o.w = acc[3]*inv + b.w;
    *(float4*)&out[(size_t)n*64 + j*4] = o;
  }
}

// ---------------- launch ----------------
extern "C" void kernel_launch(void* const* d_in, const int* in_sizes, int n_in,
                              void* d_out, int out_size, void* d_ws, size_t ws_size,
                              hipStream_t stream) {
  const float* emb = (const float*)d_in[0];
  const int*   src = (const int*)d_in[1];
  const int*   dst = (const int*)d_in[2];
  const float* W1  = (const float*)d_in[3];
  const float* al1 = (const float*)d_in[4];
  const float* ar1 = (const float*)d_in[5];
  const float* b1  = (const float*)d_in[6];
  const float* W2  = (const float*)d_in[7];
  const float* al2 = (const float*)d_in[8];
  const float* ar2 = (const float*)d_in[9];
  const float* b2  = (const float*)d_in[10];
  float* out = (float*)d_out;

  const int N = in_sizes[0] / 128;
  const int E = in_sizes[1];

  char* p = (char*)d_ws;
  auto alloc = [&](size_t bytes) -> void* {
    void* r = (void*)p; p += (bytes + 255) & ~(size_t)255; return r;
  };
  __hip_bfloat16* feat1b = (__hip_bfloat16*)alloc((size_t)N*256*2);
  __hip_bfloat16* h1b    = (__hip_bfloat16*)alloc((size_t)N*256*2);
  __hip_bfloat16* feat2b = (__hip_bfloat16*)alloc((size_t)N*64*2);
  float* el1             = (float*)alloc((size_t)N*4*4);
  float* er1             = (float*)alloc((size_t)N*4*4);
  float* el2             = (float*)alloc((size_t)N*4);
  float* er2             = (float*)alloc((size_t)N*4);
  int*   deg             = (int*)alloc((size_t)N*4);
  int*   row_start       = (int*)alloc((size_t)(N+1)*4);
  int*   cursor          = (int*)alloc((size_t)N*4);
  int*   blocksum        = (int*)alloc((size_t)DIV_UP(N,1024)*4);
  int*   srcp            = (int*)alloc((size_t)E*4);
  int*   dstp            = (int*)alloc((size_t)E*4);
  float* w4              = (float*)alloc((size_t)E*16);
  float* w1              = w4;   // layer-2 weights reuse (consumed before overwrite)

  const int nb = DIV_UP(N, 1024);

  hipMemsetAsync(deg, 0, (size_t)N*4, stream);
  k_count_deg<<<DIV_UP(E,256), 256, 0, stream>>>(dst, deg, E);
  k_scan1<<<nb, 256, 0, stream>>>(deg, blocksum, N);
  k_scan2<<<1, 64, 0, stream>>>(blocksum, nb);
  k_scan3<<<nb, 256, 0, stream>>>(deg, blocksum, row_start, cursor, N);

  // Layer 1
  k_gemm_mfma<128,4,false><<<dim3(DIV_UP(N,64), 4), 256, 0, stream>>>(
      emb, W1, 256, (unsigned short*)feat1b, al1, ar1, el1, er1, N);
  k_fillw4<<<DIV_UP(E,256), 256, 0, stream>>>(dst, src, cursor, srcp, dstp,
      (const float4*)el1, (const float4*)er1, (float4*)w4, E);
  k_gath4<<<DIV_UP(N,4), 256, 0, stream>>>((const char*)feat1b, w4, row_start,
                                           srcp, b1, h1b, N);
  // Layer 2
  k_gemm_mfma<256,1,true><<<dim3(DIV_UP(N,64), 1), 256, 0, stream>>>(
      h1b, W2, 64, (unsigned short*)feat2b, al2, ar2, el2, er2, N);
  k_edgew1<<<DIV_UP(E,256), 256, 0, stream>>>(srcp, dstp, el2, er2, w1, E);
  k_gath1<<<DIV_UP(N,4), 256, 0, stream>>>((const char*)feat2b, w1, row_start,
                                           srcp, b2, out, N);
}

// Round 7
// 237.721 us; speedup vs baseline: 2.2026x; 1.0412x over previous
//
#include <hip/hip_runtime.h>
#include <hip/hip_bf16.h>
#include <math.h>

#define DIV_UP(a,b) (((a)+(b)-1)/(b))

typedef __attribute__((ext_vector_type(8))) short short8v;
typedef __attribute__((ext_vector_type(4))) float f32x4;

__device__ __forceinline__ float bf_lo(unsigned u){ union{unsigned x; float f;} v; v.x = u << 16; return v.f; }
__device__ __forceinline__ float bf_hi(unsigned u){ union{unsigned x; float f;} v; v.x = u & 0xffff0000u; return v.f; }
__device__ __forceinline__ unsigned short f2bf(float f){
  union{float f; unsigned u;} v; v.f = f;
  unsigned r = v.u + 0x7fff + ((v.u >> 16) & 1);   // round-nearest-even
  return (unsigned short)(r >> 16);
}
__device__ __forceinline__ unsigned packbf(float a, float b){
  return (unsigned)f2bf(a) | ((unsigned)f2bf(b) << 16);
}
__device__ __forceinline__ float lrelu(float x){ return x > 0.f ? x : 0.2f*x; }

// ---------------- CSR build ----------------
__global__ void k_count_deg(const int* __restrict__ dst, int* __restrict__ deg, int E){
  int i = blockIdx.x*blockDim.x + threadIdx.x;
  if (i < E) atomicAdd(&deg[dst[i]], 1);
}

__global__ __launch_bounds__(256) void k_scan1(const int* __restrict__ deg,
                                               int* __restrict__ blocksum, int N){
  int b = blockIdx.x;
  int base = b*1024 + threadIdx.x*4;
  int s = 0;
  if (base + 3 < N){
    int4 v = *(const int4*)&deg[base];
    s = v.x + v.y + v.z + v.w;
  } else {
    for (int i = 0; i < 4; i++){ int idx = base + i; if (idx < N) s += deg[idx]; }
  }
  #pragma unroll
  for (int o = 32; o; o >>= 1) s += __shfl_down(s, o);
  __shared__ int ws[4];
  int wid = threadIdx.x >> 6, lane = threadIdx.x & 63;
  if (lane == 0) ws[wid] = s;
  __syncthreads();
  if (threadIdx.x == 0) blocksum[b] = ws[0] + ws[1] + ws[2] + ws[3];
}

__global__ void k_scan2(int* __restrict__ blocksum, int nb){
  int lane = threadIdx.x;  // 64 threads
  int carry = 0;
  for (int base = 0; base < nb; base += 64){
    int idx = base + lane;
    int orig = (idx < nb) ? blocksum[idx] : 0;
    int v = orig;
    #pragma unroll
    for (int o = 1; o < 64; o <<= 1){ int t = __shfl_up(v, o); if (lane >= o) v += t; }
    if (idx < nb) blocksum[idx] = carry + v - orig;   // exclusive
    carry += __shfl(v, 63);
  }
}

__global__ __launch_bounds__(256) void k_scan3(const int* __restrict__ deg,
                                               const int* __restrict__ blockoff,
                                               int* __restrict__ row_start,
                                               int* __restrict__ cursor, int N){
  int b = blockIdx.x;
  int base = b*1024 + threadIdx.x*4;
  int v[4];
  #pragma unroll
  for (int i = 0; i < 4; i++){ int idx = base + i; v[i] = (idx < N) ? deg[idx] : 0; }
  int s = v[0] + v[1] + v[2] + v[3];
  int lane = threadIdx.x & 63, wid = threadIdx.x >> 6;
  int inc = s;
  #pragma unroll
  for (int o = 1; o < 64; o <<= 1){ int t = __shfl_up(inc, o); if (lane >= o) inc += t; }
  __shared__ int wsum[4];
  if (lane == 63) wsum[wid] = inc;
  __syncthreads();
  int woff = 0;
  #pragma unroll
  for (int i = 0; i < 4; i++) if (i < wid) woff += wsum[i];
  int run = blockoff[b] + woff + inc - s;
  #pragma unroll
  for (int i = 0; i < 4; i++){
    int idx = base + i;
    if (idx < N){ row_start[idx] = run; cursor[idx] = run; run += v[i]; }
  }
  if (base < N && base + 4 >= N) row_start[N] = run;
}

// fill + layer-1 edge weights fused: one pass over original edges.
__global__ void k_fillw4(const int* __restrict__ dst, const int* __restrict__ src,
                         int* __restrict__ cursor, int* __restrict__ srcp,
                         int* __restrict__ dstp,
                         const float4* __restrict__ el4, const float4* __restrict__ er4,
                         float4* __restrict__ w4, int E){
  int i = blockIdx.x*blockDim.x + threadIdx.x;
  if (i < E){
    int d = dst[i], s = src[i];
    int p = atomicAdd(&cursor[d], 1);
    srcp[p] = s; dstp[p] = d;
    float4 l = el4[s], r = er4[d];
    float4 w;
    w.x = __expf(lrelu(l.x + r.x));
    w.y = __expf(lrelu(l.y + r.y));
    w.z = __expf(lrelu(l.z + r.z));
    w.w = __expf(lrelu(l.w + r.w));
    w4[p] = w;
  }
}

// layer-2 edge weights
__global__ void k_edgew1(const int* __restrict__ srcp, const int* __restrict__ dstp,
                         const float* __restrict__ el, const float* __restrict__ er,
                         float* __restrict__ w1, int E){
  int i = blockIdx.x*blockDim.x + threadIdx.x;
  if (i < E) w1[i] = __expf(lrelu(el[srcp[i]] + er[dstp[i]]));
}

// ---------------- MFMA bf16 GEMM, 64x64 tile, full-K LDS, fused el/er ----------------
template<int K, int H, bool ABF>
__global__ __launch_bounds__(256) void k_gemm_mfma(const void* __restrict__ Av,
      const float* __restrict__ B, int ldb,
      unsigned short* __restrict__ Cbf,
      const float* __restrict__ al, const float* __restrict__ ar,
      float* __restrict__ el, float* __restrict__ er, int M){
  constexpr int KP = K + 8;
  __shared__ alignas(16) __hip_bfloat16 At[64][KP];
  __shared__ alignas(16) __hip_bfloat16 Bt[64][KP];
  __shared__ float elp[2][64], erp[2][64];
  const int tid = threadIdx.x;
  const int lane = tid & 63, w = tid >> 6;
  const int mw = w >> 1, nw = w & 1;
  const int m0 = blockIdx.x * 64, by = blockIdx.y, n0 = by * 64;

  if constexpr (!ABF){
    const float* A = (const float*)Av;
    #pragma unroll
    for (int i = 0; i < K/16; i++){
      int q = tid + i*256;
      int row = q / (K/4), c4 = q % (K/4);
      float4 a = make_float4(0.f,0.f,0.f,0.f);
      if (m0 + row < M) a = *(const float4*)&A[(size_t)(m0+row)*K + c4*4];
      *(uint2*)&At[row][c4*4] = make_uint2(packbf(a.x,a.y), packbf(a.z,a.w));
    }
  } else {
    const __hip_bfloat16* A = (const __hip_bfloat16*)Av;
    #pragma unroll
    for (int i = 0; i < K/32; i++){
      int q = tid + i*256;
      int row = q / (K/8), c8 = q % (K/8);
      uint4 u = make_uint4(0,0,0,0);
      if (m0 + row < M) u = *(const uint4*)&A[(size_t)(m0+row)*K + c8*8];
      *(uint4*)&At[row][c8*8] = u;
    }
  }
  #pragma unroll
  for (int i = 0; i < K/16; i++){
    int q = tid + i*256;
    int c = q & 63, k4 = q >> 6;
    float b0 = B[(size_t)(k4*4+0)*ldb + n0 + c];
    float b1 = B[(size_t)(k4*4+1)*ldb + n0 + c];
    float b2 = B[(size_t)(k4*4+2)*ldb + n0 + c];
    float b3 = B[(size_t)(k4*4+3)*ldb + n0 + c];
    *(uint2*)&Bt[c][k4*4] = make_uint2(packbf(b0,b1), packbf(b2,b3));
  }
  __syncthreads();

  f32x4 acc[2][2];
  #pragma unroll
  for (int i = 0; i < 2; i++)
    #pragma unroll
    for (int j = 0; j < 2; j++)
      #pragma unroll
      for (int r = 0; r < 4; r++) acc[i][j][r] = 0.f;

  const int rbase = mw*32, cbase = nw*32;
  const int fr = lane & 15, fg = lane >> 4;
  #pragma unroll
  for (int ks = 0; ks < K/32; ks++){
    short8v a0 = *(const short8v*)&At[rbase + fr     ][ks*32 + fg*8];
    short8v a1 = *(const short8v*)&At[rbase + 16 + fr][ks*32 + fg*8];
    short8v b0 = *(const short8v*)&Bt[cbase + fr     ][ks*32 + fg*8];
    short8v b1 = *(const short8v*)&Bt[cbase + 16 + fr][ks*32 + fg*8];
    acc[0][0] = __builtin_amdgcn_mfma_f32_16x16x32_bf16(a0, b0, acc[0][0], 0,0,0);
    acc[0][1] = __builtin_amdgcn_mfma_f32_16x16x32_bf16(a0, b1, acc[0][1], 0,0,0);
    acc[1][0] = __builtin_amdgcn_mfma_f32_16x16x32_bf16(a1, b0, acc[1][0], 0,0,0);
    acc[1][1] = __builtin_amdgcn_mfma_f32_16x16x32_bf16(a1, b1, acc[1][1], 0,0,0);
  }

  float alv[2], arv[2];
  #pragma unroll
  for (int nt = 0; nt < 2; nt++){
    int col = cbase + nt*16 + fr;
    alv[nt] = al[by*64 + col];
    arv[nt] = ar[by*64 + col];
  }
  #pragma unroll
  for (int mt = 0; mt < 2; mt++){
    #pragma unroll
    for (int r = 0; r < 4; r++){
      float pl = acc[mt][0][r]*alv[0] + acc[mt][1][r]*alv[1];
      float pr = acc[mt][0][r]*arv[0] + acc[mt][1][r]*arv[1];
      #pragma unroll
      for (int o = 1; o < 16; o <<= 1){ pl += __shfl_xor(pl, o); pr += __shfl_xor(pr, o); }
      if (fr == 0){
        int rl = rbase + mt*16 + fg*4 + r;
        elp[nw][rl] = pl; erp[nw][rl] = pr;
      }
    }
  }
  const int NN = H*64;
  #pragma unroll
  for (int mt = 0; mt < 2; mt++){
    #pragma unroll
    for (int r = 0; r < 4; r++){
      int row = m0 + rbase + mt*16 + fg*4 + r;
      if (row < M){
        #pragma unroll
        for (int nt = 0; nt < 2; nt++)
          Cbf[(size_t)row*NN + n0 + cbase + nt*16 + fr] = f2bf(acc[mt][nt][r]);
      }
    }
  }
  __syncthreads();
  if (tid < 64){
    int row = m0 + tid;
    if (row < M){
      el[(size_t)row*H + by] = elp[0][tid] + elp[1][tid];
      er[(size_t)row*H + by] = erp[0][tid] + erp[1][tid];
    }
  }
}

// ---------------- pure gather-aggregate, H=4 (layer 1), grid-stride ----------------
__global__ __launch_bounds__(256) void k_gath4(const char* __restrict__ featb,
      const float* __restrict__ w4, const int* __restrict__ row_start,
      const int* __restrict__ srcp, const float* __restrict__ bias,
      __hip_bfloat16* __restrict__ outb, int N, int nwaves){
  int wv = threadIdx.x >> 6, lane = threadIdx.x & 63;
  int g = lane >> 4, j = lane & 15, h = j >> 2;
  const char* fb = featb + (unsigned)(j << 5);

  int n = blockIdx.x*4 + wv;
  if (n >= N) return;
  int rs = row_start[n], re = row_start[n+1];

  while (true){
    int deg = re - rs;
    int nn = n + nwaves;
    int rs_n = 0, re_n = 0;
    if (nn < N){ rs_n = row_start[nn]; re_n = row_start[nn+1]; }  // prefetch next node

    float acc[16];
    #pragma unroll
    for (int k = 0; k < 16; k++) acc[k] = 0.f;
    float Sacc = 0.f;

    int i = 0;
    int full = deg & ~15;          // unguarded 16-edge quads
    for (; i < full; i += 16){
      float wb[4]; uint4 u0[4], u1[4];
      #pragma unroll
      for (int k = 0; k < 4; k++){
        int e = rs + i + k*4 + g;
        int sb = srcp[e];
        wb[k] = w4[(size_t)e*4 + h];
        const char* p = fb + (size_t)sb*512u;
        u0[k] = *(const uint4*)p;
        u1[k] = *(const uint4*)(p + 16);
      }
      #pragma unroll
      for (int k = 0; k < 4; k++){
        float wk = wb[k];
        Sacc += wk;
        acc[0]  += bf_lo(u0[k].x)*wk; acc[1]  += bf_hi(u0[k].x)*wk;
        acc[2]  += bf_lo(u0[k].y)*wk; acc[3]  += bf_hi(u0[k].y)*wk;
        acc[4]  += bf_lo(u0[k].z)*wk; acc[5]  += bf_hi(u0[k].z)*wk;
        acc[6]  += bf_lo(u0[k].w)*wk; acc[7]  += bf_hi(u0[k].w)*wk;
        acc[8]  += bf_lo(u1[k].x)*wk; acc[9]  += bf_hi(u1[k].x)*wk;
        acc[10] += bf_lo(u1[k].y)*wk; acc[11] += bf_hi(u1[k].y)*wk;
        acc[12] += bf_lo(u1[k].z)*wk; acc[13] += bf_hi(u1[k].z)*wk;
        acc[14] += bf_lo(u1[k].w)*wk; acc[15] += bf_hi(u1[k].w)*wk;
      }
    }
    if (i < deg){                  // guarded tail (<=15 edges)
      float wb[4]; uint4 u0[4], u1[4];
      #pragma unroll
      for (int k = 0; k < 4; k++){
        int e = i + k*4 + g;
        wb[k] = 0.f;
        u0[k] = make_uint4(0,0,0,0); u1[k] = make_uint4(0,0,0,0);
        if (e < deg){
          int sb = srcp[rs + e];
          wb[k] = w4[(size_t)(rs + e)*4 + h];
          const char* p = fb + (size_t)sb*512u;
          u0[k] = *(const uint4*)p;
          u1[k] = *(const uint4*)(p + 16);
        }
      }
      #pragma unroll
      for (int k = 0; k < 4; k++){
        float wk = wb[k];
        Sacc += wk;
        acc[0]  += bf_lo(u0[k].x)*wk; acc[1]  += bf_hi(u0[k].x)*wk;
        acc[2]  += bf_lo(u0[k].y)*wk; acc[3]  += bf_hi(u0[k].y)*wk;
        acc[4]  += bf_lo(u0[k].z)*wk; acc[5]  += bf_hi(u0[k].z)*wk;
        acc[6]  += bf_lo(u0[k].w)*wk; acc[7]  += bf_hi(u0[k].w)*wk;
        acc[8]  += bf_lo(u1[k].x)*wk; acc[9]  += bf_hi(u1[k].x)*wk;
        acc[10] += bf_lo(u1[k].y)*wk; acc[11] += bf_hi(u1[k].y)*wk;
        acc[12] += bf_lo(u1[k].z)*wk; acc[13] += bf_hi(u1[k].z)*wk;
        acc[14] += bf_lo(u1[k].w)*wk; acc[15] += bf_hi(u1[k].w)*wk;
      }
    }

    #pragma unroll
    for (int k = 0; k < 16; k++){
      acc[k] += __shfl_xor(acc[k], 16);
      acc[k] += __shfl_xor(acc[k], 32);
    }
    Sacc += __shfl_xor(Sacc, 16);
    Sacc += __shfl_xor(Sacc, 32);
    if (g == 0){
      float inv = (deg > 0 && Sacc > 0.f) ? 1.f / Sacc : 0.f;
      float4 b0 = *(const float4*)&bias[j*16 + 0];
      float4 b1 = *(const float4*)&bias[j*16 + 4];
      float4 b2 = *(const float4*)&bias[j*16 + 8];
      float4 b3 = *(const float4*)&bias[j*16 + 12];
      float v[16];
      v[0]=acc[0]*inv+b0.x;  v[1]=acc[1]*inv+b0.y;  v[2]=acc[2]*inv+b0.z;  v[3]=acc[3]*inv+b0.w;
      v[4]=acc[4]*inv+b1.x;  v[5]=acc[5]*inv+b1.y;  v[6]=acc[6]*inv+b1.z;  v[7]=acc[7]*inv+b1.w;
      v[8]=acc[8]*inv+b2.x;  v[9]=acc[9]*inv+b2.y;  v[10]=acc[10]*inv+b2.z; v[11]=acc[11]*inv+b2.w;
      v[12]=acc[12]*inv+b3.x; v[13]=acc[13]*inv+b3.y; v[14]=acc[14]*inv+b3.z; v[15]=acc[15]*inv+b3.w;
      #pragma unroll
      for (int k = 0; k < 16; k++) v[k] = fmaxf(v[k], 0.f);   // relu (layer 1)
      uint4 o0, o1;
      o0.x = packbf(v[0], v[1]);   o0.y = packbf(v[2], v[3]);
      o0.z = packbf(v[4], v[5]);   o0.w = packbf(v[6], v[7]);
      o1.x = packbf(v[8], v[9]);   o1.y = packbf(v[10], v[11]);
      o1.z = packbf(v[12], v[13]); o1.w = packbf(v[14], v[15]);
      uint4* op = (uint4*)outb + (size_t)n*32 + (j << 1);
      op[0] = o0; op[1] = o1;
    }

    if (nn >= N) break;
    n = nn; rs = rs_n; re = re_n;
  }
}

// ---------------- pure gather-aggregate, H=1 (layer 2), grid-stride, fp32 out ----------------
__global__ __launch_bounds__(256) void k_gath1(const char* __restrict__ featb,
      const float* __restrict__ w1, const int* __restrict__ row_start,
      const int* __restrict__ srcp, const float* __restrict__ bias,
      float* __restrict__ out, int N, int nwaves){
  int wv = threadIdx.x >> 6, lane = threadIdx.x & 63;
  int g = lane >> 4, j = lane & 15;
  const char* fb = featb + (unsigned)(j << 3);

  int n = blockIdx.x*4 + wv;
  if (n >= N) return;
  int rs = row_start[n], re = row_start[n+1];

  while (true){
    int deg = re - rs;
    int nn = n + nwaves;
    int rs_n = 0, re_n = 0;
    if (nn < N){ rs_n = row_start[nn]; re_n = row_start[nn+1]; }

    float acc[4] = {0.f, 0.f, 0.f, 0.f};
    float Sacc = 0.f;

    int i = 0;
    int full = deg & ~15;
    for (; i < full; i += 16){
      float wb[4]; uint2 u[4];
      #pragma unroll
      for (int k = 0; k < 4; k++){
        int e = rs + i + k*4 + g;
        int sb = srcp[e];
        wb[k] = w1[e];
        u[k] = *(const uint2*)(fb + (size_t)sb*128u);
      }
      #pragma unroll
      for (int k = 0; k < 4; k++){
        float wk = wb[k];
        Sacc += wk;
        acc[0] += bf_lo(u[k].x)*wk; acc[1] += bf_hi(u[k].x)*wk;
        acc[2] += bf_lo(u[k].y)*wk; acc[3] += bf_hi(u[k].y)*wk;
      }
    }
    if (i < deg){
      float wb[4]; uint2 u[4];
      #pragma unroll
      for (int k = 0; k < 4; k++){
        int e = i + k*4 + g;
        wb[k] = 0.f;
        u[k] = make_uint2(0,0);
        if (e < deg){
          int sb = srcp[rs + e];
          wb[k] = w1[rs + e];
          u[k] = *(const uint2*)(fb + (size_t)sb*128u);
        }
      }
      #pragma unroll
      for (int k = 0; k < 4; k++){
        float wk = wb[k];
        Sacc += wk;
        acc[0] += bf_lo(u[k].x)*wk; acc[1] += bf_hi(u[k].x)*wk;
        acc[2] += bf_lo(u[k].y)*wk; acc[3] += bf_hi(u[k].y)*wk;
      }
    }

    #pragma unroll
    for (int k = 0; k < 4; k++){
      acc[k] += __shfl_xor(acc[k], 16);
      acc[k] += __shfl_xor(acc[k], 32);
    }
    Sacc += __shfl_xor(Sacc, 16);
    Sacc += __shfl_xor(Sacc, 32);
    if (g == 0){
      float inv = (deg > 0 && Sacc > 0.f) ? 1.f / Sacc : 0.f;
      float4 b = *(const float4*)&bias[j*4];
      float4 o;
      o.x = acc[0]*inv + b.x; o.y = acc[1]*inv + b.y;
      o.z = acc[2]*inv + b.z; o.w = acc[3]*inv + b.w;
      *(float4*)&out[(size_t)n*64 + j*4] = o;
    }

    if (nn >= N) break;
    n = nn; rs = rs_n; re = re_n;
  }
}

// ---------------- launch ----------------
extern "C" void kernel_launch(void* const* d_in, const int* in_sizes, int n_in,
                              void* d_out, int out_size, void* d_ws, size_t ws_size,
                              hipStream_t stream) {
  const float* emb = (const float*)d_in[0];
  const int*   src = (const int*)d_in[1];
  const int*   dst = (const int*)d_in[2];
  const float* W1  = (const float*)d_in[3];
  const float* al1 = (const float*)d_in[4];
  const float* ar1 = (const float*)d_in[5];
  const float* b1  = (const float*)d_in[6];
  const float* W2  = (const float*)d_in[7];
  const float* al2 = (const float*)d_in[8];
  const float* ar2 = (const float*)d_in[9];
  const float* b2  = (const float*)d_in[10];
  float* out = (float*)d_out;

  const int N = in_sizes[0] / 128;
  const int E = in_sizes[1];

  char* p = (char*)d_ws;
  auto alloc = [&](size_t bytes) -> void* {
    void* r = (void*)p; p += (bytes + 255) & ~(size_t)255; return r;
  };
  __hip_bfloat16* feat1b = (__hip_bfloat16*)alloc((size_t)N*256*2);
  __hip_bfloat16* h1b    = (__hip_bfloat16*)alloc((size_t)N*256*2);
  __hip_bfloat16* feat2b = (__hip_bfloat16*)alloc((size_t)N*64*2);
  float* el1             = (float*)alloc((size_t)N*4*4);
  float* er1             = (float*)alloc((size_t)N*4*4);
  float* el2             = (float*)alloc((size_t)N*4);
  float* er2             = (float*)alloc((size_t)N*4);
  int*   deg             = (int*)alloc((size_t)N*4);
  int*   row_start       = (int*)alloc((size_t)(N+1)*4);
  int*   cursor          = (int*)alloc((size_t)N*4);
  int*   blocksum        = (int*)alloc((size_t)DIV_UP(N,1024)*4);
  int*   srcp            = (int*)alloc((size_t)E*4);
  int*   dstp            = (int*)alloc((size_t)E*4);
  float* w4              = (float*)alloc((size_t)E*16);
  float* w1              = w4;   // layer-2 weights reuse

  const int nb = DIV_UP(N, 1024);
  const int gblocks = min(DIV_UP(N, 4), 2048);
  const int nwaves  = gblocks * 4;

  hipMemsetAsync(deg, 0, (size_t)N*4, stream);
  k_count_deg<<<DIV_UP(E,256), 256, 0, stream>>>(dst, deg, E);
  k_scan1<<<nb, 256, 0, stream>>>(deg, blocksum, N);
  k_scan2<<<1, 64, 0, stream>>>(blocksum, nb);
  k_scan3<<<nb, 256, 0, stream>>>(deg, blocksum, row_start, cursor, N);

  // Layer 1
  k_gemm_mfma<128,4,false><<<dim3(DIV_UP(N,64), 4), 256, 0, stream>>>(
      emb, W1, 256, (unsigned short*)feat1b, al1, ar1, el1, er1, N);
  k_fillw4<<<DIV_UP(E,256), 256, 0, stream>>>(dst, src, cursor, srcp, dstp,
      (const float4*)el1, (const float4*)er1, (float4*)w4, E);
  k_gath4<<<gblocks, 256, 0, stream>>>((const char*)feat1b, w4, row_start,
                                       srcp, b1, h1b, N, nwaves);
  // Layer 2
  k_gemm_mfma<256,1,true><<<dim3(DIV_UP(N,64), 1), 256, 0, stream>>>(
      h1b, W2, 64, (unsigned short*)feat2b, al2, ar2, el2, er2, N);
  k_edgew1<<<DIV_UP(E,256), 256, 0, stream>>>(srcp, dstp, el2, er2, w1, E);
  k_gath1<<<gblocks, 256, 0, stream>>>((const char*)feat2b, w1, row_start,
                                       srcp, b2, out, N, nwaves);
}